// Round 4
// baseline (255.919 us; speedup 1.0000x reference)
//
#include <hip/hip_runtime.h>
#include <math.h>

// R11 = R10 skeleton (persistent + neighbor flags) + two changes:
//  1) XCD-region swizzle: bid%8 selects one of 8 macro-regions (2 batches x
//     2x2 quadrants of 8x8 tiles), so ~75% of ring-neighbor pairs share an
//     XCD L2 (default round-robin put every neighbor on a different XCD).
//  2) Full address hoisting: flat LDS arena + fp16 "family" layout
//     [xb|q0|q1|q2] per parity; per-thread ring-stage (global,LDS) pairs,
//     slot reload/store offsets, and LDS bases precomputed ONCE before the
//     g-loop. Per-group staging/epilogue has zero address math.
//  Math is bit-identical to R10/R7. Fallback 12-launch path preserved.
#define XDIM 160
#define YDIM 160
#define TDIM 16
#define NB 2
#define T_ITERS 48
#define TILE 10
#define R1S 16
#define R0S 18
#define TPT (XDIM / TILE)
#define NTHR 512
#define NGRP (T_ITERS / 4)
#define FLAG_STRIDE 16
#define NRING 5           // max precomputed ring items per thread

constexpr int VOL  = XDIM * YDIM * TDIM;  // 409600
constexpr int NX   = NB * VOL;            // 819200
constexpr int NBLK = NB * TPT * TPT;      // 512

// flat LDS arena bases (floats)
constexpr int Q0B = R0S * R0S * TDIM;          // 5184
constexpr int Q1B = Q0B + 17 * 16 * TDIM;      // 9536
constexpr int SLDS = Q1B + 16 * 17 * TDIM;     // 13888 floats = 54.25 KB

typedef _Float16 hreal;
typedef _Float16 half4 __attribute__((ext_vector_type(4)));

__device__ __forceinline__ float clampl(float v, float l) {
    return fminf(fmaxf(v, -l), l);
}
__device__ __forceinline__ int wrap(int v) {
    return v < 0 ? v + XDIM : (v >= XDIM ? v - XDIM : v);
}
__device__ __forceinline__ int wrapT(int v) {
    return v < 0 ? v + TPT : (v >= TPT ? v - TPT : v);
}
__device__ __forceinline__ void ld4(const float* p, float* d) {
    float4 v = *(const float4*)p;
    d[0] = v.x; d[1] = v.y; d[2] = v.z; d[3] = v.w;
}
__device__ __forceinline__ void st4(float* p, const float* s) {
    *(float4*)p = make_float4(s[0], s[1], s[2], s[3]);
}
__device__ __forceinline__ void h2f4(const hreal* p, float* d) {
    half4 v = *(const half4*)p;
    d[0] = (float)v.x; d[1] = (float)v.y; d[2] = (float)v.z; d[3] = (float)v.w;
}
__device__ __forceinline__ float qrot_up(float x) {
    return __int_as_float(__builtin_amdgcn_update_dpp(
        0, __float_as_int(x), 0x39, 0xF, 0xF, true));
}
__device__ __forceinline__ float qrot_dn(float x) {
    return __int_as_float(__builtin_amdgcn_update_dpp(
        0, __float_as_int(x), 0x93, 0xF, 0xF, true));
}

__global__ __launch_bounds__(256) void init_kernel(
    const float* __restrict__ x, const float* __restrict__ lam,
    float* __restrict__ pA, float* __restrict__ xA,
    hreal* __restrict__ famA,          // [xb | q0 | q1 | q2] = 4*NX halves
    hreal* __restrict__ lamh, hreal* __restrict__ xnh,
    unsigned* __restrict__ flags)
{
    int i = blockIdx.x * blockDim.x + threadIdx.x;
    if (i < NX) {
        float v = x[i];
        pA[i] = v; xA[i] = v;
        famA[i] = (hreal)v;            // xb plane
        xnh[i]  = (hreal)v;
    }
    if (i < 3 * NX) {
        famA[NX + i] = (hreal)0.f;     // q planes
        lamh[i] = (hreal)lam[i];
    }
    if (flags && i < NBLK * FLAG_STRIDE) flags[i] = 0u;
}

// ---------------------------------------------------------------------------
// R11 persistent kernel
// ---------------------------------------------------------------------------
__global__ __launch_bounds__(NTHR, 4) void pd_persist(
    const hreal* __restrict__ xnh, const hreal* __restrict__ lamh,
    float* __restrict__ pA, float* __restrict__ pB,
    float* __restrict__ xA, float* __restrict__ xB,
    hreal* __restrict__ famA, hreal* __restrict__ famB,
    unsigned* __restrict__ flags,
    float sigma, float inv1ps, float tau, float theta)
{
    __shared__ float S[SLDS];

    const int tid = threadIdx.x;
    // XCD-region swizzle: region = bid%8 = {b, tile-quadrant}; 64 tiles each.
    const int region = blockIdx.x & 7;
    const int local  = blockIdx.x >> 3;
    const int b  = region >> 2;
    const int tx = ((region >> 1) & 1) * 8 + (local >> 3);
    const int ty = (region & 1) * 8 + (local & 7);
    const int X0 = tx * TILE, Y0 = ty * TILE;
    const int t0 = (tid & 3) * 4;
    const int QD = NX + 2 * b * VOL;   // xb-plane off -> q0-plane off delta

    const int myFlag = b * TPT * TPT + tx * TPT + ty;
    const unsigned* nbFlag = nullptr;
    if (tid < 8) {
        const int dxs[8] = {-1,-1,-1, 0, 0, 1, 1, 1};
        const int dys[8] = {-1, 0, 1,-1, 1,-1, 0, 1};
        int nx = wrapT(tx + dxs[tid]);
        int ny = wrapT(ty + dys[tid]);
        nbFlag = flags + (b * TPT * TPT + nx * TPT + ny) * FLAG_STRIDE;
    }

    // ---- one-time hoisting ----
    float p[2][4], xv[2][4], xb[2][4], q0[2][4], q1[2][4], q2[2][4];
    half4 XNr[2], L0r[2], L1r[2], L2r[2];
    int lx_[2], ly_[2], ro_[2], so_[2];
    int a_xb[2], a_q0w[2], a_q1w[2];
    bool c_[2], pxs_[2], qs_[2];

    #pragma unroll
    for (int m = 0; m < 2; ++m) {
        int line = 128 * m + (tid >> 2);
        int lx = line >> 4, ly = line & 15;
        lx_[m] = lx; ly_[m] = ly;
        int gx = wrap(X0 - 3 + lx), gy = wrap(Y0 - 3 + ly);
        ro_[m] = b * VOL + (gx * YDIM + gy) * TDIM + t0;       // halo offset
        so_[m] = b * VOL + ((X0 + lx - 3) * YDIM + (Y0 + ly - 3)) * TDIM + t0;
        a_xb[m]  = ((lx + 1) * R0S + (ly + 1)) * TDIM + t0;
        a_q0w[m] = Q0B + ((lx + 1) * 16 + ly) * TDIM + t0;
        a_q1w[m] = Q1B + (lx * 17 + (ly + 1)) * TDIM + t0;
        c_[m]   = lx >= 3 && lx < 13 && ly >= 3 && ly < 13;
        int ox = lx - 3, oy = ly - 3;
        pxs_[m] = (ox >= 3 && ox < 7 && oy >= 3 && oy < 7);
        qs_[m]  = (ox >= 4 && ox < 6 && oy >= 4 && oy < 6);
        // constants (once for all 48 iterations)
        int qoff = ro_[m] + 2 * b * VOL;   // b*3VOL + lineoff
        XNr[m] = *(const half4*)(xnh + ro_[m]);
        L0r[m] = *(const half4*)(lamh + qoff);
        L1r[m] = *(const half4*)(lamh + qoff + VOL);
        L2r[m] = *(const half4*)(lamh + qoff + 2 * VOL);
    }
    half4 LRr;
    int rQ = 0, rXBC = 0;
    if (tid < 64) {
        int rly = tid >> 2;
        LRr = *(const half4*)(lamh + b * 3 * VOL +
              (wrap(X0 - 4) * YDIM + wrap(Y0 - 3 + rly)) * TDIM + t0);
        rQ   = Q0B + rly * TDIM + t0;
        rXBC = (rly + 1) * TDIM + t0;
    } else if (tid < 128) {
        int rlx = (tid - 64) >> 2;
        LRr = *(const half4*)(lamh + b * 3 * VOL + VOL +
              (wrap(X0 - 3 + rlx) * YDIM + wrap(Y0 - 4)) * TDIM + t0);
        rQ   = Q1B + (rlx * 17) * TDIM + t0;
        rXBC = ((rlx + 1) * R0S) * TDIM + t0;
    }

    // ring-stage work list: 2192 items (xb 896, q0 648, q1 648)
    int r_goff[NRING], r_loff[NRING];
    #pragma unroll
    for (int i = 0; i < NRING; ++i) {
        int t = tid + NTHR * i;
        int go = -1, lo = 0;
        if (t < 896) {
            int sq = t & 3, r = t >> 2, rx, ry;
            if (r < 72)       { rx = r / 18; ry = r % 18; }
            else if (r < 152) { int u = r - 72; rx = 4 + u / 8; int c = u % 8; ry = c < 4 ? c : c + 10; }
            else              { int u = r - 152; rx = 14 + u / 18; ry = u % 18; }
            int gx = wrap(X0 - 4 + rx), gy = wrap(Y0 - 4 + ry);
            go = b * VOL + (gx * YDIM + gy) * TDIM + sq * 4;
            lo = (rx * R0S + ry) * TDIM + sq * 4;
        } else if (t < 1544) {
            int v = t - 896; int sq = v & 3, r = v >> 2, sx, sy;
            if (r < 48)       { sx = r / 16; sy = r % 16; }
            else if (r < 114) { int u = r - 48; sx = 3 + u / 6; int c = u % 6; sy = c < 3 ? c : c + 10; }
            else              { int u = r - 114; sx = 14 + u / 16; sy = u % 16; }
            int gx = wrap(X0 - 4 + sx), gy = wrap(Y0 - 3 + sy);
            go = NX + b * 3 * VOL + (gx * YDIM + gy) * TDIM + sq * 4;
            lo = Q0B + (sx * 16 + sy) * TDIM + sq * 4;
        } else if (t < 2192) {
            int v = t - 1544; int sq = v & 3, r = v >> 2, sx, sy;
            if (r < 51)       { sx = r / 17; sy = r % 17; }
            else if (r < 111) { int u = r - 51; sx = 3 + u / 6; int c = u % 6; sy = c < 3 ? c : c + 11; }
            else              { int u = r - 111; sx = 13 + u / 17; sy = u % 17; }
            int gx = wrap(X0 - 3 + sx), gy = wrap(Y0 - 4 + sy);
            go = NX + b * 3 * VOL + VOL + (gx * YDIM + gy) * TDIM + sq * 4;
            lo = Q1B + (sx * 17 + sy) * TDIM + sq * 4;
        }
        r_goff[i] = go; r_loff[i] = lo;
    }

    #pragma unroll 1
    for (int g = 0; g < NGRP; ++g) {
        const bool e = (g & 1) == 0;
        const bool first = (g == 0);
        const bool fin   = (g == NGRP - 1);
        const float* __restrict__ pIn  = e ? pA : pB;
        float* __restrict__ pOut       = e ? pB : pA;
        const float* __restrict__ xIn  = e ? xA : xB;
        float* __restrict__ xOut       = e ? xB : xA;
        const hreal* __restrict__ famIn = e ? famA : famB;
        hreal* __restrict__ famOut      = e ? famB : famA;

        // ---- neighbor sync ----
        if (!first) {
            if (tid < 8) {
                const unsigned tgt = (unsigned)g;
                for (unsigned it = 0; it < (1u << 22); ++it) {
                    if (__hip_atomic_load(nbFlag, __ATOMIC_ACQUIRE,
                                          __HIP_MEMORY_SCOPE_AGENT) >= tgt)
                        break;
                    __builtin_amdgcn_s_sleep(1);
                }
            }
            __syncthreads();
            __threadfence();
        }

        // ---- stage halos ----
        if (first) {
            for (int s = tid; s < R0S * R0S * 4; s += NTHR) {
                int sq = s & 3, ln = s >> 2;
                int rx = ln / R0S, ry = ln % R0S;
                int gx = wrap(X0 - 4 + rx), gy = wrap(Y0 - 4 + ry);
                float v[4];
                h2f4(famIn + b * VOL + (gx * YDIM + gy) * TDIM + sq * 4, v);
                st4(S + ln * TDIM + sq * 4, v);
            }
            for (int s = tid; s < 17 * 16 * 4; s += NTHR) {
                int sq = s & 3, ln = s >> 2;
                int sx = ln / 16, sy = ln % 16;
                int gx = wrap(X0 - 4 + sx), gy = wrap(Y0 - 3 + sy);
                float v[4];
                h2f4(famIn + NX + b * 3 * VOL + (gx * YDIM + gy) * TDIM + sq * 4, v);
                st4(S + Q0B + ln * TDIM + sq * 4, v);
            }
            for (int s = tid; s < 16 * 17 * 4; s += NTHR) {
                int sq = s & 3, ln = s >> 2;
                int sx = ln / 17, sy = ln % 17;
                int gx = wrap(X0 - 3 + sx), gy = wrap(Y0 - 4 + sy);
                float v[4];
                h2f4(famIn + NX + b * 3 * VOL + VOL + (gx * YDIM + gy) * TDIM + sq * 4, v);
                st4(S + Q1B + ln * TDIM + sq * 4, v);
            }
        } else {
            #pragma unroll
            for (int i = 0; i < NRING; ++i) {
                if (r_goff[i] >= 0) {
                    float v[4];
                    h2f4(famIn + r_goff[i], v);
                    st4(S + r_loff[i], v);
                }
            }
        }

        // ---- per-slot reload (ring slots; all on g==0) ----
        #pragma unroll
        for (int m = 0; m < 2; ++m) {
            if (first || !c_[m]) {
                ld4(pIn + ro_[m], p[m]);
                ld4(xIn + ro_[m], xv[m]);
                h2f4(famIn + ro_[m] + QD + 2 * VOL, q2[m]);
            }
        }
        __syncthreads();
        #pragma unroll
        for (int m = 0; m < 2; ++m)
            if (first || !c_[m])
                ld4(S + a_xb[m], xb[m]);

        // ---- level loop ----
        #pragma unroll
        for (int k = 1; k <= 4; ++k) {
            const int lo = k - 1, hi = 17 - k;

            if (k == 1) {
                if (tid < 64) {
                    float qr[4], xbc[4], xpx[4];
                    ld4(S + rQ, qr);
                    ld4(S + rXBC, xbc);
                    ld4(S + rXBC + R0S * TDIM, xpx);
                    #pragma unroll
                    for (int j = 0; j < 4; ++j)
                        qr[j] = clampl(qr[j] + sigma * (xpx[j] - xbc[j]), (float)LRr[j]);
                    st4(S + rQ, qr);
                } else if (tid < 128) {
                    float qr[4], xbc[4], xpy[4];
                    ld4(S + rQ, qr);
                    ld4(S + rXBC, xbc);
                    ld4(S + rXBC + TDIM, xpy);
                    #pragma unroll
                    for (int j = 0; j < 4; ++j)
                        qr[j] = clampl(qr[j] + sigma * (xpy[j] - xbc[j]), (float)LRr[j]);
                    st4(S + rQ, qr);
                }
            }

            // ===== phase B =====
            #pragma unroll
            for (int m = 0; m < 2; ++m) {
                int lx = lx_[m], ly = ly_[m];
                bool inX = (lx >= lo && lx < hi), inY = (ly >= lo && ly < hi);
                bool aq0 = inY && (lx >= lo - 1) && (lx < hi);
                bool aq1 = inX && (ly >= lo - 1) && (ly < hi);
                bool ax  = inX && inY;

                if (k == 1 && (first || !c_[m])) {
                    ld4(S + a_q0w[m], q0[m]);
                    ld4(S + a_q1w[m], q1[m]);
                }
                if (aq0) {
                    float xpx[4];
                    ld4(S + a_xb[m] + R0S * TDIM, xpx);
                    #pragma unroll
                    for (int j = 0; j < 4; ++j)
                        q0[m][j] = clampl(q0[m][j] + sigma * (xpx[j] - xb[m][j]),
                                          (float)L0r[m][j]);
                    st4(S + a_q0w[m], q0[m]);
                }
                if (aq1) {
                    float xpy[4];
                    ld4(S + a_xb[m] + TDIM, xpy);
                    #pragma unroll
                    for (int j = 0; j < 4; ++j)
                        q1[m][j] = clampl(q1[m][j] + sigma * (xpy[j] - xb[m][j]),
                                          (float)L1r[m][j]);
                    st4(S + a_q1w[m], q1[m]);
                }
                if (ax) {
                    float xb_tp = qrot_up(xb[m][0]);
                    #pragma unroll
                    for (int j = 0; j < 4; ++j) {
                        float gt = ((j < 3) ? xb[m][j + 1] : xb_tp) - xb[m][j];
                        q2[m][j] = clampl(q2[m][j] + sigma * gt, (float)L2r[m][j]);
                        p[m][j]  = (p[m][j] + sigma * (xb[m][j] - (float)XNr[m][j]))
                                   * inv1ps;
                    }
                }
            }
            __syncthreads();

            // ===== phase C =====
            #pragma unroll
            for (int m = 0; m < 2; ++m) {
                int lx = lx_[m], ly = ly_[m];
                bool ax = (lx >= lo && lx < hi && ly >= lo && ly < hi);
                if (ax) {
                    float q0b[4], q1b[4];
                    ld4(S + a_q0w[m] - 16 * TDIM, q0b);
                    ld4(S + a_q1w[m] - TDIM, q1b);
                    float q2tm = qrot_dn(q2[m][3]);
                    #pragma unroll
                    for (int j = 0; j < 4; ++j) {
                        float q2p = (j == 0) ? q2tm : q2[m][j - 1];
                        float div = (q0b[j] - q0[m][j]) + (q1b[j] - q1[m][j])
                                  + (q2p - q2[m][j]);
                        float xnew = xv[m][j] - tau * (p[m][j] + div);
                        xb[m][j] = xnew + theta * (xnew - xv[m][j]);
                        xv[m][j] = xnew;
                    }
                    st4(S + a_xb[m], xb[m]);
                }
            }
            if (k < 4) __syncthreads();
        }

        // ---- epilogue ----
        #pragma unroll
        for (int m = 0; m < 2; ++m) {
            if (c_[m]) {
                int so = so_[m];
                if (fin) {
                    st4(xOut + so, xv[m]);
                } else {
                    if (!pxs_[m]) {
                        st4(pOut + so, p[m]);
                        st4(xOut + so, xv[m]);
                    }
                    if (!qs_[m]) {
                        half4 h;
                        h.x = (hreal)xb[m][0]; h.y = (hreal)xb[m][1];
                        h.z = (hreal)xb[m][2]; h.w = (hreal)xb[m][3];
                        *(half4*)(famOut + so) = h;
                        h.x = (hreal)q0[m][0]; h.y = (hreal)q0[m][1];
                        h.z = (hreal)q0[m][2]; h.w = (hreal)q0[m][3];
                        *(half4*)(famOut + so + QD) = h;
                        h.x = (hreal)q1[m][0]; h.y = (hreal)q1[m][1];
                        h.z = (hreal)q1[m][2]; h.w = (hreal)q1[m][3];
                        *(half4*)(famOut + so + QD + VOL) = h;
                        h.x = (hreal)q2[m][0]; h.y = (hreal)q2[m][1];
                        h.z = (hreal)q2[m][2]; h.w = (hreal)q2[m][3];
                        *(half4*)(famOut + so + QD + 2 * VOL) = h;
                    }
                }
            }
        }

        if (!fin) {
            __threadfence();
            __syncthreads();
            if (tid == 0)
                __hip_atomic_store(flags + myFlag * FLAG_STRIDE, (unsigned)(g + 1),
                                   __ATOMIC_RELEASE, __HIP_MEMORY_SCOPE_AGENT);
        }
    }
}

// ---------------------------------------------------------------------------
// Fallback: proven R7 12-launch kernel (family pointers, same semantics)
// ---------------------------------------------------------------------------
__global__ __launch_bounds__(NTHR, 4) void pd_step4(
    const hreal* __restrict__ xnh, const hreal* __restrict__ lamh,
    const float* __restrict__ pIn, float* __restrict__ pOut,
    const float* __restrict__ xIn, float* __restrict__ xOut,
    const hreal* __restrict__ xbIn, hreal* __restrict__ xbOut,
    const hreal* __restrict__ qIn, hreal* __restrict__ qOut,
    float sigma, float inv1ps, float tau, float theta)
{
    __shared__ float xbS[R0S * R0S * TDIM];
    __shared__ float q0S[17 * 16 * TDIM];
    __shared__ float q1S[16 * 17 * TDIM];

    const int tid = threadIdx.x;
    const int b   = blockIdx.x / (TPT * TPT);
    const int rem = blockIdx.x % (TPT * TPT);
    const int X0  = (rem / TPT) * TILE;
    const int Y0  = (rem % TPT) * TILE;
    const int xbase = b * VOL, qbase = b * 3 * VOL;

    const int qd = tid & 3, t0 = qd * 4;
    const int lane  = tid & 63;
    const int upSrc = (lane & 60) | ((lane + 1) & 3);
    const int dnSrc = (lane & 60) | ((lane + 3) & 3);

    for (int s = tid; s < R0S * R0S * 4; s += NTHR) {
        int sq = s & 3, ln = s >> 2;
        int rx = ln / R0S, ry = ln % R0S;
        int gx = wrap(X0 - 4 + rx), gy = wrap(Y0 - 4 + ry);
        float v[4];
        h2f4(xbIn + xbase + (gx * YDIM + gy) * TDIM + sq * 4, v);
        st4(xbS + ln * TDIM + sq * 4, v);
    }
    for (int s = tid; s < 17 * 16 * 4; s += NTHR) {
        int sq = s & 3, ln = s >> 2;
        int sx = ln / 16, sy = ln % 16;
        int gx = wrap(X0 - 4 + sx), gy = wrap(Y0 - 3 + sy);
        float v[4];
        h2f4(qIn + qbase + (gx * YDIM + gy) * TDIM + sq * 4, v);
        st4(q0S + ln * TDIM + sq * 4, v);
    }
    for (int s = tid; s < 16 * 17 * 4; s += NTHR) {
        int sq = s & 3, ln = s >> 2;
        int sx = ln / 17, sy = ln % 17;
        int gx = wrap(X0 - 3 + sx), gy = wrap(Y0 - 4 + sy);
        float v[4];
        h2f4(qIn + qbase + VOL + (gx * YDIM + gy) * TDIM + sq * 4, v);
        st4(q1S + ln * TDIM + sq * 4, v);
    }

    float p[2][4], xv[2][4], xb[2][4], q0[2][4], q1[2][4], q2[2][4];
    half4 XNr[2], L0r[2], L1r[2], L2r[2];
    #pragma unroll
    for (int m = 0; m < 2; ++m) {
        int line = 128 * m + (tid >> 2);
        int lx = line >> 4, ly = line & 15;
        int gx = wrap(X0 - 3 + lx), gy = wrap(Y0 - 3 + ly);
        int off  = xbase + (gx * YDIM + gy) * TDIM + t0;
        int qoff = qbase + (gx * YDIM + gy) * TDIM + t0;
        ld4(pIn + off, p[m]);
        ld4(xIn + off, xv[m]);
        h2f4(qIn + qoff + 2 * VOL, q2[m]);
        XNr[m] = *(const half4*)(xnh + off);
        L0r[m] = *(const half4*)(lamh + qoff);
        L1r[m] = *(const half4*)(lamh + qoff + VOL);
        L2r[m] = *(const half4*)(lamh + qoff + 2 * VOL);
    }

    half4 LRr;
    if (tid < 64) {
        int rly = tid >> 2;
        LRr = *(const half4*)(lamh + qbase +
              (wrap(X0 - 4) * YDIM + wrap(Y0 - 3 + rly)) * TDIM + t0);
    } else if (tid < 128) {
        int rlx = (tid - 64) >> 2;
        LRr = *(const half4*)(lamh + qbase + VOL +
              (wrap(X0 - 3 + rlx) * YDIM + wrap(Y0 - 4)) * TDIM + t0);
    }

    __syncthreads();

    #pragma unroll
    for (int m = 0; m < 2; ++m) {
        int line = 128 * m + (tid >> 2);
        int lx = line >> 4, ly = line & 15;
        ld4(xbS + ((lx + 1) * R0S + (ly + 1)) * TDIM + t0, xb[m]);
    }

    #pragma unroll
    for (int k = 1; k <= 4; ++k) {
        const int lo = k - 1, hi = 17 - k;

        if (k == 1) {
            if (tid < 64) {
                int rly = tid >> 2;
                float qr[4], xbc[4], xpx[4];
                ld4(q0S + rly * TDIM + t0, qr);
                ld4(xbS + (rly + 1) * TDIM + t0, xbc);
                ld4(xbS + (R0S + rly + 1) * TDIM + t0, xpx);
                #pragma unroll
                for (int j = 0; j < 4; ++j)
                    qr[j] = clampl(qr[j] + sigma * (xpx[j] - xbc[j]), (float)LRr[j]);
                st4(q0S + rly * TDIM + t0, qr);
            } else if (tid < 128) {
                int rlx = (tid - 64) >> 2;
                float qr[4], xbc[4], xpy[4];
                ld4(q1S + (rlx * 17) * TDIM + t0, qr);
                ld4(xbS + ((rlx + 1) * R0S) * TDIM + t0, xbc);
                ld4(xbS + ((rlx + 1) * R0S + 1) * TDIM + t0, xpy);
                #pragma unroll
                for (int j = 0; j < 4; ++j)
                    qr[j] = clampl(qr[j] + sigma * (xpy[j] - xbc[j]), (float)LRr[j]);
                st4(q1S + (rlx * 17) * TDIM + t0, qr);
            }
        }

        #pragma unroll
        for (int m = 0; m < 2; ++m) {
            int line = 128 * m + (tid >> 2);
            int lx = line >> 4, ly = line & 15;
            bool inX = (lx >= lo && lx < hi), inY = (ly >= lo && ly < hi);
            bool aq0 = inY && (lx >= lo - 1) && (lx < hi);
            bool aq1 = inX && (ly >= lo - 1) && (ly < hi);
            bool ax  = inX && inY;

            if (k == 1) {
                ld4(q0S + ((lx + 1) * 16 + ly) * TDIM + t0, q0[m]);
                ld4(q1S + (lx * 17 + (ly + 1)) * TDIM + t0, q1[m]);
            }
            if (aq0) {
                float xpx[4];
                ld4(xbS + ((lx + 2) * R0S + (ly + 1)) * TDIM + t0, xpx);
                #pragma unroll
                for (int j = 0; j < 4; ++j)
                    q0[m][j] = clampl(q0[m][j] + sigma * (xpx[j] - xb[m][j]),
                                      (float)L0r[m][j]);
                st4(q0S + ((lx + 1) * 16 + ly) * TDIM + t0, q0[m]);
            }
            if (aq1) {
                float xpy[4];
                ld4(xbS + ((lx + 1) * R0S + (ly + 2)) * TDIM + t0, xpy);
                #pragma unroll
                for (int j = 0; j < 4; ++j)
                    q1[m][j] = clampl(q1[m][j] + sigma * (xpy[j] - xb[m][j]),
                                      (float)L1r[m][j]);
                st4(q1S + (lx * 17 + (ly + 1)) * TDIM + t0, q1[m]);
            }
            if (ax) {
                float xb_tp = __shfl(xb[m][0], upSrc, 64);
                #pragma unroll
                for (int j = 0; j < 4; ++j) {
                    float gt = ((j < 3) ? xb[m][j + 1] : xb_tp) - xb[m][j];
                    q2[m][j] = clampl(q2[m][j] + sigma * gt, (float)L2r[m][j]);
                    p[m][j]  = (p[m][j] + sigma * (xb[m][j] - (float)XNr[m][j]))
                               * inv1ps;
                }
            }
        }
        __syncthreads();

        #pragma unroll
        for (int m = 0; m < 2; ++m) {
            int line = 128 * m + (tid >> 2);
            int lx = line >> 4, ly = line & 15;
            bool ax = (lx >= lo && lx < hi && ly >= lo && ly < hi);
            if (ax) {
                float q0b[4], q1b[4];
                ld4(q0S + (lx * 16 + ly) * TDIM + t0, q0b);
                ld4(q1S + (lx * 17 + ly) * TDIM + t0, q1b);
                float q2tm = __shfl(q2[m][3], dnSrc, 64);
                #pragma unroll
                for (int j = 0; j < 4; ++j) {
                    float q2p = (j == 0) ? q2tm : q2[m][j - 1];
                    float div = (q0b[j] - q0[m][j]) + (q1b[j] - q1[m][j])
                              + (q2p - q2[m][j]);
                    float xnew = xv[m][j] - tau * (p[m][j] + div);
                    xb[m][j] = xnew + theta * (xnew - xv[m][j]);
                    xv[m][j] = xnew;
                }
                if (k < 4)
                    st4(xbS + ((lx + 1) * R0S + (ly + 1)) * TDIM + t0, xb[m]);
            }
        }
        if (k < 4) __syncthreads();
    }

    #pragma unroll
    for (int m = 0; m < 2; ++m) {
        int line = 128 * m + (tid >> 2);
        int lx = line >> 4, ly = line & 15;
        if (lx >= 3 && lx < 13 && ly >= 3 && ly < 13) {
            int gx = X0 + lx - 3, gy = Y0 + ly - 3;
            int off  = xbase + (gx * YDIM + gy) * TDIM + t0;
            int qoff = qbase + (gx * YDIM + gy) * TDIM + t0;
            st4(pOut + off, p[m]);
            st4(xOut + off, xv[m]);
            half4 h;
            h.x = (hreal)xb[m][0]; h.y = (hreal)xb[m][1];
            h.z = (hreal)xb[m][2]; h.w = (hreal)xb[m][3];
            *(half4*)(xbOut + off) = h;
            h.x = (hreal)q0[m][0]; h.y = (hreal)q0[m][1];
            h.z = (hreal)q0[m][2]; h.w = (hreal)q0[m][3];
            *(half4*)(qOut + qoff) = h;
            h.x = (hreal)q1[m][0]; h.y = (hreal)q1[m][1];
            h.z = (hreal)q1[m][2]; h.w = (hreal)q1[m][3];
            *(half4*)(qOut + qoff + VOL) = h;
            h.x = (hreal)q2[m][0]; h.y = (hreal)q2[m][1];
            h.z = (hreal)q2[m][2]; h.w = (hreal)q2[m][3];
            *(half4*)(qOut + qoff + 2 * VOL) = h;
        }
    }
}

extern "C" void kernel_launch(void* const* d_in, const int* in_sizes, int n_in,
                              void* d_out, int out_size, void* d_ws, size_t ws_size,
                              hipStream_t stream) {
    const float* x   = (const float*)d_in[0];
    const float* lam = (const float*)d_in[1];
    float* out = (float*)d_out;
    float* ws  = (float*)d_ws;

    float* pA  = ws;
    float* pB  = ws + (size_t)NX;
    float* xBb = ws + (size_t)2 * NX;
    float* xAb = out;   // final group (odd parity) writes A family -> d_out
    hreal* hb  = (hreal*)(ws + (size_t)3 * NX);
    hreal* famA = hb;                    // [xb|q0|q1|q2] = 4*NX
    hreal* famB = hb + (size_t)4 * NX;
    hreal* lamh = hb + (size_t)8 * NX;   // 3*NX
    hreal* xnh  = hb + (size_t)11 * NX;  // NX
    unsigned* flags = (unsigned*)(ws + (size_t)9 * NX);

    const size_t ws_need = (size_t)9 * NX * sizeof(float)
                         + (size_t)NBLK * FLAG_STRIDE * sizeof(unsigned);

    const double s10 = 1.0 / (1.0 + exp(-10.0));
    const double L   = sqrt(13.0);
    float sigma  = (float)(s10 / L);
    float tau    = sigma;
    float theta  = (float)s10;
    float inv1ps = (float)(1.0 / (1.0 + s10 / L));

    static int persist_ok = -1;
    if (persist_ok < 0) {
        int nb = 0;
        hipError_t oe = hipOccupancyMaxActiveBlocksPerMultiprocessor(
            &nb, pd_persist, NTHR, 0);
        persist_ok = (oe == hipSuccess && nb >= 2) ? 1 : 0;
        (void)hipGetLastError();
    }
    const bool use_persist = persist_ok == 1 && ws_size >= ws_need;

    init_kernel<<<(3 * NX + 255) / 256, 256, 0, stream>>>(
        x, lam, pA, xAb, famA, lamh, xnh, use_persist ? flags : nullptr);

    if (use_persist) {
        pd_persist<<<NBLK, NTHR, 0, stream>>>(
            xnh, lamh, pA, pB, xAb, xBb, famA, famB, flags,
            sigma, inv1ps, tau, theta);
    } else {
        for (int j = 0; j < NGRP; ++j) {
            const bool e = (j & 1) == 0;
            pd_step4<<<NBLK, NTHR, 0, stream>>>(
                xnh, lamh,
                e ? pA : pB,   e ? pB : pA,
                e ? xAb : xBb, e ? xBb : xAb,
                e ? famA : famB, e ? famB : famA,
                e ? famA + NX : famB + NX, e ? famB + NX : famA + NX,
                sigma, inv1ps, tau, theta);
        }
    }
}

// Round 5
// 254.268 us; speedup vs baseline: 1.0065x; 1.0065x over previous
//
#include <hip/hip_runtime.h>
#include <math.h>

// R12 = R10/R11 skeleton (persistent + neighbor flags + XCD-region swizzle +
// dead-write trim) with a REGISTER-PRESSURE and CRITICAL-PATH attack:
//  1) xb/q0/q1 are no longer loop-carried in registers across groups — their
//     exact fp32 copies already live in LDS (C(k=4) writes xbS center,
//     B(k=4) writes q0S/q1S center, staging refreshes rings). Loaded from
//     LDS each group. Loop-carried set: p, xv, q2 + constants only
//     (~60 values vs ~90 -> no scratch spill of persistent state).
//  2) R11's hoisted ring-address arrays reverted (VALU-cheap, VGPR-costly).
//  3) q2/p updates moved from phase B (pre-barrier) to phase C (post-barrier);
//     C issues its LDS loads first so their latency hides under q2/p VALU.
//  Math is bit-identical. Fallback 12-launch path preserved.
#define XDIM 160
#define YDIM 160
#define TDIM 16
#define NB 2
#define T_ITERS 48
#define TILE 10
#define R1S 16
#define R0S 18
#define TPT (XDIM / TILE)
#define NTHR 512
#define NGRP (T_ITERS / 4)
#define FLAG_STRIDE 16

constexpr int VOL  = XDIM * YDIM * TDIM;  // 409600
constexpr int NX   = NB * VOL;            // 819200
constexpr int NBLK = NB * TPT * TPT;      // 512

// flat LDS arena bases (floats)
constexpr int Q0B = R0S * R0S * TDIM;          // 5184
constexpr int Q1B = Q0B + 17 * 16 * TDIM;      // 9536
constexpr int SLDS = Q1B + 16 * 17 * TDIM;     // 13888 floats = 54.25 KB

typedef _Float16 hreal;
typedef _Float16 half4 __attribute__((ext_vector_type(4)));

__device__ __forceinline__ float clampl(float v, float l) {
    return fminf(fmaxf(v, -l), l);
}
__device__ __forceinline__ int wrap(int v) {
    return v < 0 ? v + XDIM : (v >= XDIM ? v - XDIM : v);
}
__device__ __forceinline__ int wrapT(int v) {
    return v < 0 ? v + TPT : (v >= TPT ? v - TPT : v);
}
__device__ __forceinline__ void ld4(const float* p, float* d) {
    float4 v = *(const float4*)p;
    d[0] = v.x; d[1] = v.y; d[2] = v.z; d[3] = v.w;
}
__device__ __forceinline__ void st4(float* p, const float* s) {
    *(float4*)p = make_float4(s[0], s[1], s[2], s[3]);
}
__device__ __forceinline__ void h2f4(const hreal* p, float* d) {
    half4 v = *(const half4*)p;
    d[0] = (float)v.x; d[1] = (float)v.y; d[2] = (float)v.z; d[3] = (float)v.w;
}
__device__ __forceinline__ float qrot_up(float x) {
    return __int_as_float(__builtin_amdgcn_update_dpp(
        0, __float_as_int(x), 0x39, 0xF, 0xF, true));
}
__device__ __forceinline__ float qrot_dn(float x) {
    return __int_as_float(__builtin_amdgcn_update_dpp(
        0, __float_as_int(x), 0x93, 0xF, 0xF, true));
}

__global__ __launch_bounds__(256) void init_kernel(
    const float* __restrict__ x, const float* __restrict__ lam,
    float* __restrict__ pA, float* __restrict__ xA,
    hreal* __restrict__ famA,          // [xb | q0 | q1 | q2] = 4*NX halves
    hreal* __restrict__ lamh, hreal* __restrict__ xnh,
    unsigned* __restrict__ flags)
{
    int i = blockIdx.x * blockDim.x + threadIdx.x;
    if (i < NX) {
        float v = x[i];
        pA[i] = v; xA[i] = v;
        famA[i] = (hreal)v;            // xb plane
        xnh[i]  = (hreal)v;
    }
    if (i < 3 * NX) {
        famA[NX + i] = (hreal)0.f;     // q planes
        lamh[i] = (hreal)lam[i];
    }
    if (flags && i < NBLK * FLAG_STRIDE) flags[i] = 0u;
}

// ---------------------------------------------------------------------------
// R12 persistent kernel
// ---------------------------------------------------------------------------
__global__ __launch_bounds__(NTHR, 4) void pd_persist(
    const hreal* __restrict__ xnh, const hreal* __restrict__ lamh,
    float* __restrict__ pA, float* __restrict__ pB,
    float* __restrict__ xA, float* __restrict__ xB,
    hreal* __restrict__ famA, hreal* __restrict__ famB,
    unsigned* __restrict__ flags,
    float sigma, float inv1ps, float tau, float theta)
{
    __shared__ float S[SLDS];

    const int tid = threadIdx.x;
    // XCD-region swizzle: region = bid%8 = {b, tile-quadrant}; 64 tiles each.
    const int region = blockIdx.x & 7;
    const int local  = blockIdx.x >> 3;
    const int b  = region >> 2;
    const int tx = ((region >> 1) & 1) * 8 + (local >> 3);
    const int ty = (region & 1) * 8 + (local & 7);
    const int X0 = tx * TILE, Y0 = ty * TILE;
    const int t0 = (tid & 3) * 4;
    const int QD = NX + 2 * b * VOL;   // xb-plane off -> q0-plane off delta

    const int myFlag = (b * TPT * TPT + tx * TPT + ty) * FLAG_STRIDE;
    const unsigned* nbFlag = nullptr;
    if (tid < 8) {
        const int dxs[8] = {-1,-1,-1, 0, 0, 1, 1, 1};
        const int dys[8] = {-1, 0, 1,-1, 1,-1, 0, 1};
        int nx = wrapT(tx + dxs[tid]);
        int ny = wrapT(ty + dys[tid]);
        nbFlag = flags + (b * TPT * TPT + nx * TPT + ny) * FLAG_STRIDE;
    }

    // loop-carried: p, xv, q2 (+ constants). xb/q0/q1 live in LDS between
    // groups and in registers only WITHIN a group.
    float p[2][4], xv[2][4], q2[2][4];
    float xb[2][4], q0[2][4], q1[2][4];
    half4 XNr[2], L0r[2], L1r[2], L2r[2];
    int lx_[2], ly_[2], ro_[2], so_[2];
    int a_xb[2], a_q0w[2], a_q1w[2];
    bool c_[2], pxs_[2], qs_[2];

    #pragma unroll
    for (int m = 0; m < 2; ++m) {
        int line = 128 * m + (tid >> 2);
        int lx = line >> 4, ly = line & 15;
        lx_[m] = lx; ly_[m] = ly;
        int gx = wrap(X0 - 3 + lx), gy = wrap(Y0 - 3 + ly);
        ro_[m] = b * VOL + (gx * YDIM + gy) * TDIM + t0;
        so_[m] = b * VOL + ((X0 + lx - 3) * YDIM + (Y0 + ly - 3)) * TDIM + t0;
        a_xb[m]  = ((lx + 1) * R0S + (ly + 1)) * TDIM + t0;
        a_q0w[m] = Q0B + ((lx + 1) * 16 + ly) * TDIM + t0;
        a_q1w[m] = Q1B + (lx * 17 + (ly + 1)) * TDIM + t0;
        c_[m]   = lx >= 3 && lx < 13 && ly >= 3 && ly < 13;
        int ox = lx - 3, oy = ly - 3;
        pxs_[m] = (ox >= 3 && ox < 7 && oy >= 3 && oy < 7);
        qs_[m]  = (ox >= 4 && ox < 6 && oy >= 4 && oy < 6);
        int qoff = ro_[m] + 2 * b * VOL;
        XNr[m] = *(const half4*)(xnh + ro_[m]);
        L0r[m] = *(const half4*)(lamh + qoff);
        L1r[m] = *(const half4*)(lamh + qoff + VOL);
        L2r[m] = *(const half4*)(lamh + qoff + 2 * VOL);
    }
    half4 LRr;
    int rQ = 0, rXBC = 0;
    if (tid < 64) {
        int rly = tid >> 2;
        LRr = *(const half4*)(lamh + b * 3 * VOL +
              (wrap(X0 - 4) * YDIM + wrap(Y0 - 3 + rly)) * TDIM + t0);
        rQ   = Q0B + rly * TDIM + t0;
        rXBC = (rly + 1) * TDIM + t0;
    } else if (tid < 128) {
        int rlx = (tid - 64) >> 2;
        LRr = *(const half4*)(lamh + b * 3 * VOL + VOL +
              (wrap(X0 - 3 + rlx) * YDIM + wrap(Y0 - 4)) * TDIM + t0);
        rQ   = Q1B + (rlx * 17) * TDIM + t0;
        rXBC = ((rlx + 1) * R0S) * TDIM + t0;
    }

    #pragma unroll 1
    for (int g = 0; g < NGRP; ++g) {
        const bool e = (g & 1) == 0;
        const bool first = (g == 0);
        const bool fin   = (g == NGRP - 1);
        const float* __restrict__ pIn  = e ? pA : pB;
        float* __restrict__ pOut       = e ? pB : pA;
        const float* __restrict__ xIn  = e ? xA : xB;
        float* __restrict__ xOut       = e ? xB : xA;
        const hreal* __restrict__ famIn = e ? famA : famB;
        hreal* __restrict__ famOut      = e ? famB : famA;

        // ---- neighbor sync: need 8 neighbors' group g-1 epilogues ----
        if (!first) {
            if (tid < 8) {
                const unsigned tgt = (unsigned)g;
                for (unsigned it = 0; it < (1u << 22); ++it) {
                    if (__hip_atomic_load(nbFlag, __ATOMIC_ACQUIRE,
                                          __HIP_MEMORY_SCOPE_AGENT) >= tgt)
                        break;
                    __builtin_amdgcn_s_sleep(1);
                }
            }
            __syncthreads();
            __threadfence();
        }

        // ---- stage halos: full tile on g==0, ring-only afterwards ----
        for (int s = tid; s < R0S * R0S * 4; s += NTHR) {
            int sq = s & 3, ln = s >> 2;
            int rx = ln / R0S, ry = ln % R0S;
            if (!first && rx >= 4 && rx < 14 && ry >= 4 && ry < 14) continue;
            int gx = wrap(X0 - 4 + rx), gy = wrap(Y0 - 4 + ry);
            float v[4];
            h2f4(famIn + b * VOL + (gx * YDIM + gy) * TDIM + sq * 4, v);
            st4(S + ln * TDIM + sq * 4, v);
        }
        for (int s = tid; s < 17 * 16 * 4; s += NTHR) {
            int sq = s & 3, ln = s >> 2;
            int sx = ln / 16, sy = ln % 16;
            if (!first && sx >= 3 && sx < 14 && sy >= 3 && sy < 13) continue;
            int gx = wrap(X0 - 4 + sx), gy = wrap(Y0 - 3 + sy);
            float v[4];
            h2f4(famIn + NX + b * 3 * VOL + (gx * YDIM + gy) * TDIM + sq * 4, v);
            st4(S + Q0B + ln * TDIM + sq * 4, v);
        }
        for (int s = tid; s < 16 * 17 * 4; s += NTHR) {
            int sq = s & 3, ln = s >> 2;
            int sx = ln / 17, sy = ln % 17;
            if (!first && sx >= 3 && sx < 13 && sy >= 3 && sy < 14) continue;
            int gx = wrap(X0 - 3 + sx), gy = wrap(Y0 - 4 + sy);
            float v[4];
            h2f4(famIn + NX + b * 3 * VOL + VOL + (gx * YDIM + gy) * TDIM + sq * 4, v);
            st4(S + Q1B + ln * TDIM + sq * 4, v);
        }

        // ---- per-slot reload of p/xv/q2: ring slots only (all on g==0) ----
        #pragma unroll
        for (int m = 0; m < 2; ++m) {
            if (first || !c_[m]) {
                ld4(pIn + ro_[m], p[m]);
                ld4(xIn + ro_[m], xv[m]);
                h2f4(famIn + ro_[m] + QD + 2 * VOL, q2[m]);
            }
        }
        __syncthreads();

        // xb for ALL slots from LDS (center = last group's fp32 C(k=4) write)
        #pragma unroll
        for (int m = 0; m < 2; ++m)
            ld4(S + a_xb[m], xb[m]);

        // ---- level loop ----
        #pragma unroll
        for (int k = 1; k <= 4; ++k) {
            const int lo = k - 1, hi = 17 - k;

            if (k == 1) {
                // level-1 backward rings (outside R1): q at lx=-1 / ly=-1
                if (tid < 64) {
                    float qr[4], xbc[4], xpx[4];
                    ld4(S + rQ, qr);
                    ld4(S + rXBC, xbc);
                    ld4(S + rXBC + R0S * TDIM, xpx);
                    #pragma unroll
                    for (int j = 0; j < 4; ++j)
                        qr[j] = clampl(qr[j] + sigma * (xpx[j] - xbc[j]), (float)LRr[j]);
                    st4(S + rQ, qr);
                } else if (tid < 128) {
                    float qr[4], xbc[4], xpy[4];
                    ld4(S + rQ, qr);
                    ld4(S + rXBC, xbc);
                    ld4(S + rXBC + TDIM, xpy);
                    #pragma unroll
                    for (int j = 0; j < 4; ++j)
                        qr[j] = clampl(qr[j] + sigma * (xpy[j] - xbc[j]), (float)LRr[j]);
                    st4(S + rQ, qr);
                }
            }

            // ===== phase B: q0,q1 only (q2/p moved to C) =====
            #pragma unroll
            for (int m = 0; m < 2; ++m) {
                int lx = lx_[m], ly = ly_[m];
                bool inX = (lx >= lo && lx < hi), inY = (ly >= lo && ly < hi);
                bool aq0 = inY && (lx >= lo - 1) && (lx < hi);
                bool aq1 = inX && (ly >= lo - 1) && (ly < hi);

                if (k == 1) {   // all slots from LDS (center preserved fp32)
                    ld4(S + a_q0w[m], q0[m]);
                    ld4(S + a_q1w[m], q1[m]);
                }
                if (aq0) {
                    float xpx[4];
                    ld4(S + a_xb[m] + R0S * TDIM, xpx);
                    #pragma unroll
                    for (int j = 0; j < 4; ++j)
                        q0[m][j] = clampl(q0[m][j] + sigma * (xpx[j] - xb[m][j]),
                                          (float)L0r[m][j]);
                    st4(S + a_q0w[m], q0[m]);
                }
                if (aq1) {
                    float xpy[4];
                    ld4(S + a_xb[m] + TDIM, xpy);
                    #pragma unroll
                    for (int j = 0; j < 4; ++j)
                        q1[m][j] = clampl(q1[m][j] + sigma * (xpy[j] - xb[m][j]),
                                          (float)L1r[m][j]);
                    st4(S + a_q1w[m], q1[m]);
                }
            }
            __syncthreads();

            // ===== phase C: q2,p (moved) + x,xbar =====
            #pragma unroll
            for (int m = 0; m < 2; ++m) {
                int lx = lx_[m], ly = ly_[m];
                bool ax = (lx >= lo && lx < hi && ly >= lo && ly < hi);
                if (ax) {
                    // issue backward-q LDS loads first; latency hides under
                    // the q2/p VALU below.
                    float q0b[4], q1b[4];
                    ld4(S + a_q0w[m] - 16 * TDIM, q0b);
                    ld4(S + a_q1w[m] - TDIM, q1b);

                    float xb_tp = qrot_up(xb[m][0]);   // xbar at t0+4
                    #pragma unroll
                    for (int j = 0; j < 4; ++j) {
                        float gt = ((j < 3) ? xb[m][j + 1] : xb_tp) - xb[m][j];
                        q2[m][j] = clampl(q2[m][j] + sigma * gt, (float)L2r[m][j]);
                        p[m][j]  = (p[m][j] + sigma * (xb[m][j] - (float)XNr[m][j]))
                                   * inv1ps;
                    }

                    float q2tm = qrot_dn(q2[m][3]);    // new, t0-1
                    #pragma unroll
                    for (int j = 0; j < 4; ++j) {
                        float q2p = (j == 0) ? q2tm : q2[m][j - 1];
                        float div = (q0b[j] - q0[m][j]) + (q1b[j] - q1[m][j])
                                  + (q2p - q2[m][j]);
                        float xnew = xv[m][j] - tau * (p[m][j] + div);
                        xb[m][j] = xnew + theta * (xnew - xv[m][j]);
                        xv[m][j] = xnew;
                    }
                    // k=4 also stores: keeps LDS center valid across groups
                    st4(S + a_xb[m], xb[m]);
                }
            }
            if (k < 4) __syncthreads();
        }

        // ---- epilogue: only what someone will actually read ----
        #pragma unroll
        for (int m = 0; m < 2; ++m) {
            if (c_[m]) {
                int so = so_[m];
                if (fin) {
                    st4(xOut + so, xv[m]);
                } else {
                    if (!pxs_[m]) {
                        st4(pOut + so, p[m]);
                        st4(xOut + so, xv[m]);
                    }
                    if (!qs_[m]) {
                        half4 h;
                        h.x = (hreal)xb[m][0]; h.y = (hreal)xb[m][1];
                        h.z = (hreal)xb[m][2]; h.w = (hreal)xb[m][3];
                        *(half4*)(famOut + so) = h;
                        h.x = (hreal)q0[m][0]; h.y = (hreal)q0[m][1];
                        h.z = (hreal)q0[m][2]; h.w = (hreal)q0[m][3];
                        *(half4*)(famOut + so + QD) = h;
                        h.x = (hreal)q1[m][0]; h.y = (hreal)q1[m][1];
                        h.z = (hreal)q1[m][2]; h.w = (hreal)q1[m][3];
                        *(half4*)(famOut + so + QD + VOL) = h;
                        h.x = (hreal)q2[m][0]; h.y = (hreal)q2[m][1];
                        h.z = (hreal)q2[m][2]; h.w = (hreal)q2[m][3];
                        *(half4*)(famOut + so + QD + 2 * VOL) = h;
                    }
                }
            }
        }

        if (!fin) {
            __threadfence();
            __syncthreads();
            if (tid == 0)
                __hip_atomic_store(flags + myFlag, (unsigned)(g + 1),
                                   __ATOMIC_RELEASE, __HIP_MEMORY_SCOPE_AGENT);
        }
    }
}

// ---------------------------------------------------------------------------
// Fallback: proven R7 12-launch kernel (family pointers, same semantics)
// ---------------------------------------------------------------------------
__global__ __launch_bounds__(NTHR, 4) void pd_step4(
    const hreal* __restrict__ xnh, const hreal* __restrict__ lamh,
    const float* __restrict__ pIn, float* __restrict__ pOut,
    const float* __restrict__ xIn, float* __restrict__ xOut,
    const hreal* __restrict__ xbIn, hreal* __restrict__ xbOut,
    const hreal* __restrict__ qIn, hreal* __restrict__ qOut,
    float sigma, float inv1ps, float tau, float theta)
{
    __shared__ float xbS[R0S * R0S * TDIM];
    __shared__ float q0S[17 * 16 * TDIM];
    __shared__ float q1S[16 * 17 * TDIM];

    const int tid = threadIdx.x;
    const int b   = blockIdx.x / (TPT * TPT);
    const int rem = blockIdx.x % (TPT * TPT);
    const int X0  = (rem / TPT) * TILE;
    const int Y0  = (rem % TPT) * TILE;
    const int xbase = b * VOL, qbase = b * 3 * VOL;

    const int qd = tid & 3, t0 = qd * 4;
    const int lane  = tid & 63;
    const int upSrc = (lane & 60) | ((lane + 1) & 3);
    const int dnSrc = (lane & 60) | ((lane + 3) & 3);

    for (int s = tid; s < R0S * R0S * 4; s += NTHR) {
        int sq = s & 3, ln = s >> 2;
        int rx = ln / R0S, ry = ln % R0S;
        int gx = wrap(X0 - 4 + rx), gy = wrap(Y0 - 4 + ry);
        float v[4];
        h2f4(xbIn + xbase + (gx * YDIM + gy) * TDIM + sq * 4, v);
        st4(xbS + ln * TDIM + sq * 4, v);
    }
    for (int s = tid; s < 17 * 16 * 4; s += NTHR) {
        int sq = s & 3, ln = s >> 2;
        int sx = ln / 16, sy = ln % 16;
        int gx = wrap(X0 - 4 + sx), gy = wrap(Y0 - 3 + sy);
        float v[4];
        h2f4(qIn + qbase + (gx * YDIM + gy) * TDIM + sq * 4, v);
        st4(q0S + ln * TDIM + sq * 4, v);
    }
    for (int s = tid; s < 16 * 17 * 4; s += NTHR) {
        int sq = s & 3, ln = s >> 2;
        int sx = ln / 17, sy = ln % 17;
        int gx = wrap(X0 - 3 + sx), gy = wrap(Y0 - 4 + sy);
        float v[4];
        h2f4(qIn + qbase + VOL + (gx * YDIM + gy) * TDIM + sq * 4, v);
        st4(q1S + ln * TDIM + sq * 4, v);
    }

    float p[2][4], xv[2][4], xb[2][4], q0[2][4], q1[2][4], q2[2][4];
    half4 XNr[2], L0r[2], L1r[2], L2r[2];
    #pragma unroll
    for (int m = 0; m < 2; ++m) {
        int line = 128 * m + (tid >> 2);
        int lx = line >> 4, ly = line & 15;
        int gx = wrap(X0 - 3 + lx), gy = wrap(Y0 - 3 + ly);
        int off  = xbase + (gx * YDIM + gy) * TDIM + t0;
        int qoff = qbase + (gx * YDIM + gy) * TDIM + t0;
        ld4(pIn + off, p[m]);
        ld4(xIn + off, xv[m]);
        h2f4(qIn + qoff + 2 * VOL, q2[m]);
        XNr[m] = *(const half4*)(xnh + off);
        L0r[m] = *(const half4*)(lamh + qoff);
        L1r[m] = *(const half4*)(lamh + qoff + VOL);
        L2r[m] = *(const half4*)(lamh + qoff + 2 * VOL);
    }

    half4 LRr;
    if (tid < 64) {
        int rly = tid >> 2;
        LRr = *(const half4*)(lamh + qbase +
              (wrap(X0 - 4) * YDIM + wrap(Y0 - 3 + rly)) * TDIM + t0);
    } else if (tid < 128) {
        int rlx = (tid - 64) >> 2;
        LRr = *(const half4*)(lamh + qbase + VOL +
              (wrap(X0 - 3 + rlx) * YDIM + wrap(Y0 - 4)) * TDIM + t0);
    }

    __syncthreads();

    #pragma unroll
    for (int m = 0; m < 2; ++m) {
        int line = 128 * m + (tid >> 2);
        int lx = line >> 4, ly = line & 15;
        ld4(xbS + ((lx + 1) * R0S + (ly + 1)) * TDIM + t0, xb[m]);
    }

    #pragma unroll
    for (int k = 1; k <= 4; ++k) {
        const int lo = k - 1, hi = 17 - k;

        if (k == 1) {
            if (tid < 64) {
                int rly = tid >> 2;
                float qr[4], xbc[4], xpx[4];
                ld4(q0S + rly * TDIM + t0, qr);
                ld4(xbS + (rly + 1) * TDIM + t0, xbc);
                ld4(xbS + (R0S + rly + 1) * TDIM + t0, xpx);
                #pragma unroll
                for (int j = 0; j < 4; ++j)
                    qr[j] = clampl(qr[j] + sigma * (xpx[j] - xbc[j]), (float)LRr[j]);
                st4(q0S + rly * TDIM + t0, qr);
            } else if (tid < 128) {
                int rlx = (tid - 64) >> 2;
                float qr[4], xbc[4], xpy[4];
                ld4(q1S + (rlx * 17) * TDIM + t0, qr);
                ld4(xbS + ((rlx + 1) * R0S) * TDIM + t0, xbc);
                ld4(xbS + ((rlx + 1) * R0S + 1) * TDIM + t0, xpy);
                #pragma unroll
                for (int j = 0; j < 4; ++j)
                    qr[j] = clampl(qr[j] + sigma * (xpy[j] - xbc[j]), (float)LRr[j]);
                st4(q1S + (rlx * 17) * TDIM + t0, qr);
            }
        }

        #pragma unroll
        for (int m = 0; m < 2; ++m) {
            int line = 128 * m + (tid >> 2);
            int lx = line >> 4, ly = line & 15;
            bool inX = (lx >= lo && lx < hi), inY = (ly >= lo && ly < hi);
            bool aq0 = inY && (lx >= lo - 1) && (lx < hi);
            bool aq1 = inX && (ly >= lo - 1) && (ly < hi);
            bool ax  = inX && inY;

            if (k == 1) {
                ld4(q0S + ((lx + 1) * 16 + ly) * TDIM + t0, q0[m]);
                ld4(q1S + (lx * 17 + (ly + 1)) * TDIM + t0, q1[m]);
            }
            if (aq0) {
                float xpx[4];
                ld4(xbS + ((lx + 2) * R0S + (ly + 1)) * TDIM + t0, xpx);
                #pragma unroll
                for (int j = 0; j < 4; ++j)
                    q0[m][j] = clampl(q0[m][j] + sigma * (xpx[j] - xb[m][j]),
                                      (float)L0r[m][j]);
                st4(q0S + ((lx + 1) * 16 + ly) * TDIM + t0, q0[m]);
            }
            if (aq1) {
                float xpy[4];
                ld4(xbS + ((lx + 1) * R0S + (ly + 2)) * TDIM + t0, xpy);
                #pragma unroll
                for (int j = 0; j < 4; ++j)
                    q1[m][j] = clampl(q1[m][j] + sigma * (xpy[j] - xb[m][j]),
                                      (float)L1r[m][j]);
                st4(q1S + (lx * 17 + (ly + 1)) * TDIM + t0, q1[m]);
            }
            if (ax) {
                float xb_tp = __shfl(xb[m][0], upSrc, 64);
                #pragma unroll
                for (int j = 0; j < 4; ++j) {
                    float gt = ((j < 3) ? xb[m][j + 1] : xb_tp) - xb[m][j];
                    q2[m][j] = clampl(q2[m][j] + sigma * gt, (float)L2r[m][j]);
                    p[m][j]  = (p[m][j] + sigma * (xb[m][j] - (float)XNr[m][j]))
                               * inv1ps;
                }
            }
        }
        __syncthreads();

        #pragma unroll
        for (int m = 0; m < 2; ++m) {
            int line = 128 * m + (tid >> 2);
            int lx = line >> 4, ly = line & 15;
            bool ax = (lx >= lo && lx < hi && ly >= lo && ly < hi);
            if (ax) {
                float q0b[4], q1b[4];
                ld4(q0S + (lx * 16 + ly) * TDIM + t0, q0b);
                ld4(q1S + (lx * 17 + ly) * TDIM + t0, q1b);
                float q2tm = __shfl(q2[m][3], dnSrc, 64);
                #pragma unroll
                for (int j = 0; j < 4; ++j) {
                    float q2p = (j == 0) ? q2tm : q2[m][j - 1];
                    float div = (q0b[j] - q0[m][j]) + (q1b[j] - q1[m][j])
                              + (q2p - q2[m][j]);
                    float xnew = xv[m][j] - tau * (p[m][j] + div);
                    xb[m][j] = xnew + theta * (xnew - xv[m][j]);
                    xv[m][j] = xnew;
                }
                if (k < 4)
                    st4(xbS + ((lx + 1) * R0S + (ly + 1)) * TDIM + t0, xb[m]);
            }
        }
        if (k < 4) __syncthreads();
    }

    #pragma unroll
    for (int m = 0; m < 2; ++m) {
        int line = 128 * m + (tid >> 2);
        int lx = line >> 4, ly = line & 15;
        if (lx >= 3 && lx < 13 && ly >= 3 && ly < 13) {
            int gx = X0 + lx - 3, gy = Y0 + ly - 3;
            int off  = xbase + (gx * YDIM + gy) * TDIM + t0;
            int qoff = qbase + (gx * YDIM + gy) * TDIM + t0;
            st4(pOut + off, p[m]);
            st4(xOut + off, xv[m]);
            half4 h;
            h.x = (hreal)xb[m][0]; h.y = (hreal)xb[m][1];
            h.z = (hreal)xb[m][2]; h.w = (hreal)xb[m][3];
            *(half4*)(xbOut + off) = h;
            h.x = (hreal)q0[m][0]; h.y = (hreal)q0[m][1];
            h.z = (hreal)q0[m][2]; h.w = (hreal)q0[m][3];
            *(half4*)(qOut + qoff) = h;
            h.x = (hreal)q1[m][0]; h.y = (hreal)q1[m][1];
            h.z = (hreal)q1[m][2]; h.w = (hreal)q1[m][3];
            *(half4*)(qOut + qoff + VOL) = h;
            h.x = (hreal)q2[m][0]; h.y = (hreal)q2[m][1];
            h.z = (hreal)q2[m][2]; h.w = (hreal)q2[m][3];
            *(half4*)(qOut + qoff + 2 * VOL) = h;
        }
    }
}

extern "C" void kernel_launch(void* const* d_in, const int* in_sizes, int n_in,
                              void* d_out, int out_size, void* d_ws, size_t ws_size,
                              hipStream_t stream) {
    const float* x   = (const float*)d_in[0];
    const float* lam = (const float*)d_in[1];
    float* out = (float*)d_out;
    float* ws  = (float*)d_ws;

    float* pA  = ws;
    float* pB  = ws + (size_t)NX;
    float* xBb = ws + (size_t)2 * NX;
    float* xAb = out;   // final group (odd parity) writes A family -> d_out
    hreal* hb  = (hreal*)(ws + (size_t)3 * NX);
    hreal* famA = hb;                    // [xb|q0|q1|q2] = 4*NX
    hreal* famB = hb + (size_t)4 * NX;
    hreal* lamh = hb + (size_t)8 * NX;   // 3*NX
    hreal* xnh  = hb + (size_t)11 * NX;  // NX
    unsigned* flags = (unsigned*)(ws + (size_t)9 * NX);

    const size_t ws_need = (size_t)9 * NX * sizeof(float)
                         + (size_t)NBLK * FLAG_STRIDE * sizeof(unsigned);

    const double s10 = 1.0 / (1.0 + exp(-10.0));
    const double L   = sqrt(13.0);
    float sigma  = (float)(s10 / L);
    float tau    = sigma;
    float theta  = (float)s10;
    float inv1ps = (float)(1.0 / (1.0 + s10 / L));

    static int persist_ok = -1;
    if (persist_ok < 0) {
        int nb = 0;
        hipError_t oe = hipOccupancyMaxActiveBlocksPerMultiprocessor(
            &nb, pd_persist, NTHR, 0);
        persist_ok = (oe == hipSuccess && nb >= 2) ? 1 : 0;
        (void)hipGetLastError();
    }
    const bool use_persist = persist_ok == 1 && ws_size >= ws_need;

    init_kernel<<<(3 * NX + 255) / 256, 256, 0, stream>>>(
        x, lam, pA, xAb, famA, lamh, xnh, use_persist ? flags : nullptr);

    if (use_persist) {
        pd_persist<<<NBLK, NTHR, 0, stream>>>(
            xnh, lamh, pA, pB, xAb, xBb, famA, famB, flags,
            sigma, inv1ps, tau, theta);
    } else {
        for (int j = 0; j < NGRP; ++j) {
            const bool e = (j & 1) == 0;
            pd_step4<<<NBLK, NTHR, 0, stream>>>(
                xnh, lamh,
                e ? pA : pB,   e ? pB : pA,
                e ? xAb : xBb, e ? xBb : xAb,
                e ? famA : famB, e ? famB : famA,
                e ? famA + NX : famB + NX, e ? famB + NX : famA + NX,
                sigma, inv1ps, tau, theta);
        }
    }
}

// Round 6
// 253.093 us; speedup vs baseline: 1.0112x; 1.0046x over previous
//
#include <hip/hip_runtime.h>
#include <math.h>

// R13 = R12 skeleton with a REGISTER-ALLOCATOR attack:
//  - Every prior round showed VGPR_Count=64 while the live set is ~100 values:
//    the allocator targets the 64-VGPR occupancy granule (8 waves/EU) that the
//    54.25KB LDS (2 blocks/CU -> 4 waves/EU) makes unreachable, and thrashes
//    the overflow through scratch/LDS reloads every phase.
//  - Fix: amdgpu_flat_work_group_size(512,512) + amdgpu_waves_per_eu(4,4)
//    pins the occupancy target to the real value; <=128 VGPRs is then free.
//  - With the cap lifted, xb/q0/q1 are carried in REGISTERS across groups
//    again (center slots skip LDS reloads); q2/p stay in phase C (R12).
//  Math bit-identical. Fallback 12-launch path preserved.
#define XDIM 160
#define YDIM 160
#define TDIM 16
#define NB 2
#define T_ITERS 48
#define TILE 10
#define R1S 16
#define R0S 18
#define TPT (XDIM / TILE)
#define NTHR 512
#define NGRP (T_ITERS / 4)
#define FLAG_STRIDE 16

constexpr int VOL  = XDIM * YDIM * TDIM;  // 409600
constexpr int NX   = NB * VOL;            // 819200
constexpr int NBLK = NB * TPT * TPT;      // 512

// flat LDS arena bases (floats)
constexpr int Q0B = R0S * R0S * TDIM;          // 5184
constexpr int Q1B = Q0B + 17 * 16 * TDIM;      // 9536
constexpr int SLDS = Q1B + 16 * 17 * TDIM;     // 13888 floats = 54.25 KB

typedef _Float16 hreal;
typedef _Float16 half4 __attribute__((ext_vector_type(4)));

__device__ __forceinline__ float clampl(float v, float l) {
    return fminf(fmaxf(v, -l), l);
}
__device__ __forceinline__ int wrap(int v) {
    return v < 0 ? v + XDIM : (v >= XDIM ? v - XDIM : v);
}
__device__ __forceinline__ int wrapT(int v) {
    return v < 0 ? v + TPT : (v >= TPT ? v - TPT : v);
}
__device__ __forceinline__ void ld4(const float* p, float* d) {
    float4 v = *(const float4*)p;
    d[0] = v.x; d[1] = v.y; d[2] = v.z; d[3] = v.w;
}
__device__ __forceinline__ void st4(float* p, const float* s) {
    *(float4*)p = make_float4(s[0], s[1], s[2], s[3]);
}
__device__ __forceinline__ void h2f4(const hreal* p, float* d) {
    half4 v = *(const half4*)p;
    d[0] = (float)v.x; d[1] = (float)v.y; d[2] = (float)v.z; d[3] = (float)v.w;
}
__device__ __forceinline__ float qrot_up(float x) {
    return __int_as_float(__builtin_amdgcn_update_dpp(
        0, __float_as_int(x), 0x39, 0xF, 0xF, true));
}
__device__ __forceinline__ float qrot_dn(float x) {
    return __int_as_float(__builtin_amdgcn_update_dpp(
        0, __float_as_int(x), 0x93, 0xF, 0xF, true));
}

__global__ __launch_bounds__(256) void init_kernel(
    const float* __restrict__ x, const float* __restrict__ lam,
    float* __restrict__ pA, float* __restrict__ xA,
    hreal* __restrict__ famA,          // [xb | q0 | q1 | q2] = 4*NX halves
    hreal* __restrict__ lamh, hreal* __restrict__ xnh,
    unsigned* __restrict__ flags)
{
    int i = blockIdx.x * blockDim.x + threadIdx.x;
    if (i < NX) {
        float v = x[i];
        pA[i] = v; xA[i] = v;
        famA[i] = (hreal)v;            // xb plane
        xnh[i]  = (hreal)v;
    }
    if (i < 3 * NX) {
        famA[NX + i] = (hreal)0.f;     // q planes
        lamh[i] = (hreal)lam[i];
    }
    if (flags && i < NBLK * FLAG_STRIDE) flags[i] = 0u;
}

// ---------------------------------------------------------------------------
// R13 persistent kernel — occupancy pinned to 4 waves/EU so the allocator
// may use up to 128 VGPRs without (phantom) occupancy loss.
// ---------------------------------------------------------------------------
__global__
__attribute__((amdgpu_flat_work_group_size(NTHR, NTHR)))
__attribute__((amdgpu_waves_per_eu(4, 4)))
void pd_persist(
    const hreal* __restrict__ xnh, const hreal* __restrict__ lamh,
    float* __restrict__ pA, float* __restrict__ pB,
    float* __restrict__ xA, float* __restrict__ xB,
    hreal* __restrict__ famA, hreal* __restrict__ famB,
    unsigned* __restrict__ flags,
    float sigma, float inv1ps, float tau, float theta)
{
    __shared__ float S[SLDS];

    const int tid = threadIdx.x;
    // XCD-region swizzle: region = bid%8 = {b, tile-quadrant}; 64 tiles each.
    const int region = blockIdx.x & 7;
    const int local  = blockIdx.x >> 3;
    const int b  = region >> 2;
    const int tx = ((region >> 1) & 1) * 8 + (local >> 3);
    const int ty = (region & 1) * 8 + (local & 7);
    const int X0 = tx * TILE, Y0 = ty * TILE;
    const int t0 = (tid & 3) * 4;
    const int QD = NX + 2 * b * VOL;   // xb-plane off -> q0-plane off delta

    const int myFlag = (b * TPT * TPT + tx * TPT + ty) * FLAG_STRIDE;
    const unsigned* nbFlag = nullptr;
    if (tid < 8) {
        const int dxs[8] = {-1,-1,-1, 0, 0, 1, 1, 1};
        const int dys[8] = {-1, 0, 1,-1, 1,-1, 0, 1};
        int nx = wrapT(tx + dxs[tid]);
        int ny = wrapT(ty + dys[tid]);
        nbFlag = flags + (b * TPT * TPT + nx * TPT + ny) * FLAG_STRIDE;
    }

    // fully register-carried per-slot state (2 slots/thread)
    float p[2][4], xv[2][4], q2[2][4];
    float xb[2][4], q0[2][4], q1[2][4];
    half4 XNr[2], L0r[2], L1r[2], L2r[2];
    int lx_[2], ly_[2], ro_[2], so_[2];
    int a_xb[2], a_q0w[2], a_q1w[2];
    bool c_[2], pxs_[2], qs_[2];

    #pragma unroll
    for (int m = 0; m < 2; ++m) {
        int line = 128 * m + (tid >> 2);
        int lx = line >> 4, ly = line & 15;
        lx_[m] = lx; ly_[m] = ly;
        int gx = wrap(X0 - 3 + lx), gy = wrap(Y0 - 3 + ly);
        ro_[m] = b * VOL + (gx * YDIM + gy) * TDIM + t0;
        so_[m] = b * VOL + ((X0 + lx - 3) * YDIM + (Y0 + ly - 3)) * TDIM + t0;
        a_xb[m]  = ((lx + 1) * R0S + (ly + 1)) * TDIM + t0;
        a_q0w[m] = Q0B + ((lx + 1) * 16 + ly) * TDIM + t0;
        a_q1w[m] = Q1B + (lx * 17 + (ly + 1)) * TDIM + t0;
        c_[m]   = lx >= 3 && lx < 13 && ly >= 3 && ly < 13;
        int ox = lx - 3, oy = ly - 3;
        pxs_[m] = (ox >= 3 && ox < 7 && oy >= 3 && oy < 7);
        qs_[m]  = (ox >= 4 && ox < 6 && oy >= 4 && oy < 6);
        int qoff = ro_[m] + 2 * b * VOL;
        XNr[m] = *(const half4*)(xnh + ro_[m]);
        L0r[m] = *(const half4*)(lamh + qoff);
        L1r[m] = *(const half4*)(lamh + qoff + VOL);
        L2r[m] = *(const half4*)(lamh + qoff + 2 * VOL);
    }
    half4 LRr;
    int rQ = 0, rXBC = 0;
    if (tid < 64) {
        int rly = tid >> 2;
        LRr = *(const half4*)(lamh + b * 3 * VOL +
              (wrap(X0 - 4) * YDIM + wrap(Y0 - 3 + rly)) * TDIM + t0);
        rQ   = Q0B + rly * TDIM + t0;
        rXBC = (rly + 1) * TDIM + t0;
    } else if (tid < 128) {
        int rlx = (tid - 64) >> 2;
        LRr = *(const half4*)(lamh + b * 3 * VOL + VOL +
              (wrap(X0 - 3 + rlx) * YDIM + wrap(Y0 - 4)) * TDIM + t0);
        rQ   = Q1B + (rlx * 17) * TDIM + t0;
        rXBC = ((rlx + 1) * R0S) * TDIM + t0;
    }

    #pragma unroll 1
    for (int g = 0; g < NGRP; ++g) {
        const bool e = (g & 1) == 0;
        const bool first = (g == 0);
        const bool fin   = (g == NGRP - 1);
        const float* __restrict__ pIn  = e ? pA : pB;
        float* __restrict__ pOut       = e ? pB : pA;
        const float* __restrict__ xIn  = e ? xA : xB;
        float* __restrict__ xOut       = e ? xB : xA;
        const hreal* __restrict__ famIn = e ? famA : famB;
        hreal* __restrict__ famOut      = e ? famB : famA;

        // ---- neighbor sync: need 8 neighbors' group g-1 epilogues ----
        if (!first) {
            if (tid < 8) {
                const unsigned tgt = (unsigned)g;
                for (unsigned it = 0; it < (1u << 22); ++it) {
                    if (__hip_atomic_load(nbFlag, __ATOMIC_ACQUIRE,
                                          __HIP_MEMORY_SCOPE_AGENT) >= tgt)
                        break;
                    __builtin_amdgcn_s_sleep(1);
                }
            }
            __syncthreads();
            __threadfence();
        }

        // ---- stage halos: full tile on g==0, ring-only afterwards ----
        for (int s = tid; s < R0S * R0S * 4; s += NTHR) {
            int sq = s & 3, ln = s >> 2;
            int rx = ln / R0S, ry = ln % R0S;
            if (!first && rx >= 4 && rx < 14 && ry >= 4 && ry < 14) continue;
            int gx = wrap(X0 - 4 + rx), gy = wrap(Y0 - 4 + ry);
            float v[4];
            h2f4(famIn + b * VOL + (gx * YDIM + gy) * TDIM + sq * 4, v);
            st4(S + ln * TDIM + sq * 4, v);
        }
        for (int s = tid; s < 17 * 16 * 4; s += NTHR) {
            int sq = s & 3, ln = s >> 2;
            int sx = ln / 16, sy = ln % 16;
            if (!first && sx >= 3 && sx < 14 && sy >= 3 && sy < 13) continue;
            int gx = wrap(X0 - 4 + sx), gy = wrap(Y0 - 3 + sy);
            float v[4];
            h2f4(famIn + NX + b * 3 * VOL + (gx * YDIM + gy) * TDIM + sq * 4, v);
            st4(S + Q0B + ln * TDIM + sq * 4, v);
        }
        for (int s = tid; s < 16 * 17 * 4; s += NTHR) {
            int sq = s & 3, ln = s >> 2;
            int sx = ln / 17, sy = ln % 17;
            if (!first && sx >= 3 && sx < 13 && sy >= 3 && sy < 14) continue;
            int gx = wrap(X0 - 3 + sx), gy = wrap(Y0 - 4 + sy);
            float v[4];
            h2f4(famIn + NX + b * 3 * VOL + VOL + (gx * YDIM + gy) * TDIM + sq * 4, v);
            st4(S + Q1B + ln * TDIM + sq * 4, v);
        }

        // ---- per-slot reload: ring slots only (all slots on g==0) ----
        #pragma unroll
        for (int m = 0; m < 2; ++m) {
            if (first || !c_[m]) {
                ld4(pIn + ro_[m], p[m]);
                ld4(xIn + ro_[m], xv[m]);
                h2f4(famIn + ro_[m] + QD + 2 * VOL, q2[m]);
            }
        }
        __syncthreads();

        // xb: ring slots from LDS; center keeps register value across groups
        #pragma unroll
        for (int m = 0; m < 2; ++m)
            if (first || !c_[m])
                ld4(S + a_xb[m], xb[m]);

        // ---- level loop ----
        #pragma unroll
        for (int k = 1; k <= 4; ++k) {
            const int lo = k - 1, hi = 17 - k;

            if (k == 1) {
                // level-1 backward rings (outside R1): q at lx=-1 / ly=-1
                if (tid < 64) {
                    float qr[4], xbc[4], xpx[4];
                    ld4(S + rQ, qr);
                    ld4(S + rXBC, xbc);
                    ld4(S + rXBC + R0S * TDIM, xpx);
                    #pragma unroll
                    for (int j = 0; j < 4; ++j)
                        qr[j] = clampl(qr[j] + sigma * (xpx[j] - xbc[j]), (float)LRr[j]);
                    st4(S + rQ, qr);
                } else if (tid < 128) {
                    float qr[4], xbc[4], xpy[4];
                    ld4(S + rQ, qr);
                    ld4(S + rXBC, xbc);
                    ld4(S + rXBC + TDIM, xpy);
                    #pragma unroll
                    for (int j = 0; j < 4; ++j)
                        qr[j] = clampl(qr[j] + sigma * (xpy[j] - xbc[j]), (float)LRr[j]);
                    st4(S + rQ, qr);
                }
            }

            // ===== phase B: q0,q1 =====
            #pragma unroll
            for (int m = 0; m < 2; ++m) {
                int lx = lx_[m], ly = ly_[m];
                bool inX = (lx >= lo && lx < hi), inY = (ly >= lo && ly < hi);
                bool aq0 = inY && (lx >= lo - 1) && (lx < hi);
                bool aq1 = inX && (ly >= lo - 1) && (ly < hi);

                if (k == 1 && (first || !c_[m])) {   // center: register-carried
                    ld4(S + a_q0w[m], q0[m]);
                    ld4(S + a_q1w[m], q1[m]);
                }
                if (aq0) {
                    float xpx[4];
                    ld4(S + a_xb[m] + R0S * TDIM, xpx);
                    #pragma unroll
                    for (int j = 0; j < 4; ++j)
                        q0[m][j] = clampl(q0[m][j] + sigma * (xpx[j] - xb[m][j]),
                                          (float)L0r[m][j]);
                    st4(S + a_q0w[m], q0[m]);
                }
                if (aq1) {
                    float xpy[4];
                    ld4(S + a_xb[m] + TDIM, xpy);
                    #pragma unroll
                    for (int j = 0; j < 4; ++j)
                        q1[m][j] = clampl(q1[m][j] + sigma * (xpy[j] - xb[m][j]),
                                          (float)L1r[m][j]);
                    st4(S + a_q1w[m], q1[m]);
                }
            }
            __syncthreads();

            // ===== phase C: q2,p + x,xbar =====
            #pragma unroll
            for (int m = 0; m < 2; ++m) {
                int lx = lx_[m], ly = ly_[m];
                bool ax = (lx >= lo && lx < hi && ly >= lo && ly < hi);
                if (ax) {
                    // issue backward-q LDS loads first; latency hides under
                    // the q2/p VALU below.
                    float q0b[4], q1b[4];
                    ld4(S + a_q0w[m] - 16 * TDIM, q0b);
                    ld4(S + a_q1w[m] - TDIM, q1b);

                    float xb_tp = qrot_up(xb[m][0]);   // xbar at t0+4
                    #pragma unroll
                    for (int j = 0; j < 4; ++j) {
                        float gt = ((j < 3) ? xb[m][j + 1] : xb_tp) - xb[m][j];
                        q2[m][j] = clampl(q2[m][j] + sigma * gt, (float)L2r[m][j]);
                        p[m][j]  = (p[m][j] + sigma * (xb[m][j] - (float)XNr[m][j]))
                                   * inv1ps;
                    }

                    float q2tm = qrot_dn(q2[m][3]);    // new, t0-1
                    #pragma unroll
                    for (int j = 0; j < 4; ++j) {
                        float q2p = (j == 0) ? q2tm : q2[m][j - 1];
                        float div = (q0b[j] - q0[m][j]) + (q1b[j] - q1[m][j])
                                  + (q2p - q2[m][j]);
                        float xnew = xv[m][j] - tau * (p[m][j] + div);
                        xb[m][j] = xnew + theta * (xnew - xv[m][j]);
                        xv[m][j] = xnew;
                    }
                    // k=4 also stores: keeps LDS center valid across groups
                    st4(S + a_xb[m], xb[m]);
                }
            }
            if (k < 4) __syncthreads();
        }

        // ---- epilogue: only what someone will actually read ----
        #pragma unroll
        for (int m = 0; m < 2; ++m) {
            if (c_[m]) {
                int so = so_[m];
                if (fin) {
                    st4(xOut + so, xv[m]);
                } else {
                    if (!pxs_[m]) {
                        st4(pOut + so, p[m]);
                        st4(xOut + so, xv[m]);
                    }
                    if (!qs_[m]) {
                        half4 h;
                        h.x = (hreal)xb[m][0]; h.y = (hreal)xb[m][1];
                        h.z = (hreal)xb[m][2]; h.w = (hreal)xb[m][3];
                        *(half4*)(famOut + so) = h;
                        h.x = (hreal)q0[m][0]; h.y = (hreal)q0[m][1];
                        h.z = (hreal)q0[m][2]; h.w = (hreal)q0[m][3];
                        *(half4*)(famOut + so + QD) = h;
                        h.x = (hreal)q1[m][0]; h.y = (hreal)q1[m][1];
                        h.z = (hreal)q1[m][2]; h.w = (hreal)q1[m][3];
                        *(half4*)(famOut + so + QD + VOL) = h;
                        h.x = (hreal)q2[m][0]; h.y = (hreal)q2[m][1];
                        h.z = (hreal)q2[m][2]; h.w = (hreal)q2[m][3];
                        *(half4*)(famOut + so + QD + 2 * VOL) = h;
                    }
                }
            }
        }

        if (!fin) {
            __threadfence();
            __syncthreads();
            if (tid == 0)
                __hip_atomic_store(flags + myFlag, (unsigned)(g + 1),
                                   __ATOMIC_RELEASE, __HIP_MEMORY_SCOPE_AGENT);
        }
    }
}

// ---------------------------------------------------------------------------
// Fallback: proven R7 12-launch kernel (family pointers, same semantics)
// ---------------------------------------------------------------------------
__global__ __launch_bounds__(NTHR, 4) void pd_step4(
    const hreal* __restrict__ xnh, const hreal* __restrict__ lamh,
    const float* __restrict__ pIn, float* __restrict__ pOut,
    const float* __restrict__ xIn, float* __restrict__ xOut,
    const hreal* __restrict__ xbIn, hreal* __restrict__ xbOut,
    const hreal* __restrict__ qIn, hreal* __restrict__ qOut,
    float sigma, float inv1ps, float tau, float theta)
{
    __shared__ float xbS[R0S * R0S * TDIM];
    __shared__ float q0S[17 * 16 * TDIM];
    __shared__ float q1S[16 * 17 * TDIM];

    const int tid = threadIdx.x;
    const int b   = blockIdx.x / (TPT * TPT);
    const int rem = blockIdx.x % (TPT * TPT);
    const int X0  = (rem / TPT) * TILE;
    const int Y0  = (rem % TPT) * TILE;
    const int xbase = b * VOL, qbase = b * 3 * VOL;

    const int qd = tid & 3, t0 = qd * 4;
    const int lane  = tid & 63;
    const int upSrc = (lane & 60) | ((lane + 1) & 3);
    const int dnSrc = (lane & 60) | ((lane + 3) & 3);

    for (int s = tid; s < R0S * R0S * 4; s += NTHR) {
        int sq = s & 3, ln = s >> 2;
        int rx = ln / R0S, ry = ln % R0S;
        int gx = wrap(X0 - 4 + rx), gy = wrap(Y0 - 4 + ry);
        float v[4];
        h2f4(xbIn + xbase + (gx * YDIM + gy) * TDIM + sq * 4, v);
        st4(xbS + ln * TDIM + sq * 4, v);
    }
    for (int s = tid; s < 17 * 16 * 4; s += NTHR) {
        int sq = s & 3, ln = s >> 2;
        int sx = ln / 16, sy = ln % 16;
        int gx = wrap(X0 - 4 + sx), gy = wrap(Y0 - 3 + sy);
        float v[4];
        h2f4(qIn + qbase + (gx * YDIM + gy) * TDIM + sq * 4, v);
        st4(q0S + ln * TDIM + sq * 4, v);
    }
    for (int s = tid; s < 16 * 17 * 4; s += NTHR) {
        int sq = s & 3, ln = s >> 2;
        int sx = ln / 17, sy = ln % 17;
        int gx = wrap(X0 - 3 + sx), gy = wrap(Y0 - 4 + sy);
        float v[4];
        h2f4(qIn + qbase + VOL + (gx * YDIM + gy) * TDIM + sq * 4, v);
        st4(q1S + ln * TDIM + sq * 4, v);
    }

    float p[2][4], xv[2][4], xb[2][4], q0[2][4], q1[2][4], q2[2][4];
    half4 XNr[2], L0r[2], L1r[2], L2r[2];
    #pragma unroll
    for (int m = 0; m < 2; ++m) {
        int line = 128 * m + (tid >> 2);
        int lx = line >> 4, ly = line & 15;
        int gx = wrap(X0 - 3 + lx), gy = wrap(Y0 - 3 + ly);
        int off  = xbase + (gx * YDIM + gy) * TDIM + t0;
        int qoff = qbase + (gx * YDIM + gy) * TDIM + t0;
        ld4(pIn + off, p[m]);
        ld4(xIn + off, xv[m]);
        h2f4(qIn + qoff + 2 * VOL, q2[m]);
        XNr[m] = *(const half4*)(xnh + off);
        L0r[m] = *(const half4*)(lamh + qoff);
        L1r[m] = *(const half4*)(lamh + qoff + VOL);
        L2r[m] = *(const half4*)(lamh + qoff + 2 * VOL);
    }

    half4 LRr;
    if (tid < 64) {
        int rly = tid >> 2;
        LRr = *(const half4*)(lamh + qbase +
              (wrap(X0 - 4) * YDIM + wrap(Y0 - 3 + rly)) * TDIM + t0);
    } else if (tid < 128) {
        int rlx = (tid - 64) >> 2;
        LRr = *(const half4*)(lamh + qbase + VOL +
              (wrap(X0 - 3 + rlx) * YDIM + wrap(Y0 - 4)) * TDIM + t0);
    }

    __syncthreads();

    #pragma unroll
    for (int m = 0; m < 2; ++m) {
        int line = 128 * m + (tid >> 2);
        int lx = line >> 4, ly = line & 15;
        ld4(xbS + ((lx + 1) * R0S + (ly + 1)) * TDIM + t0, xb[m]);
    }

    #pragma unroll
    for (int k = 1; k <= 4; ++k) {
        const int lo = k - 1, hi = 17 - k;

        if (k == 1) {
            if (tid < 64) {
                int rly = tid >> 2;
                float qr[4], xbc[4], xpx[4];
                ld4(q0S + rly * TDIM + t0, qr);
                ld4(xbS + (rly + 1) * TDIM + t0, xbc);
                ld4(xbS + (R0S + rly + 1) * TDIM + t0, xpx);
                #pragma unroll
                for (int j = 0; j < 4; ++j)
                    qr[j] = clampl(qr[j] + sigma * (xpx[j] - xbc[j]), (float)LRr[j]);
                st4(q0S + rly * TDIM + t0, qr);
            } else if (tid < 128) {
                int rlx = (tid - 64) >> 2;
                float qr[4], xbc[4], xpy[4];
                ld4(q1S + (rlx * 17) * TDIM + t0, qr);
                ld4(xbS + ((rlx + 1) * R0S) * TDIM + t0, xbc);
                ld4(xbS + ((rlx + 1) * R0S + 1) * TDIM + t0, xpy);
                #pragma unroll
                for (int j = 0; j < 4; ++j)
                    qr[j] = clampl(qr[j] + sigma * (xpy[j] - xbc[j]), (float)LRr[j]);
                st4(q1S + (rlx * 17) * TDIM + t0, qr);
            }
        }

        #pragma unroll
        for (int m = 0; m < 2; ++m) {
            int line = 128 * m + (tid >> 2);
            int lx = line >> 4, ly = line & 15;
            bool inX = (lx >= lo && lx < hi), inY = (ly >= lo && ly < hi);
            bool aq0 = inY && (lx >= lo - 1) && (lx < hi);
            bool aq1 = inX && (ly >= lo - 1) && (ly < hi);
            bool ax  = inX && inY;

            if (k == 1) {
                ld4(q0S + ((lx + 1) * 16 + ly) * TDIM + t0, q0[m]);
                ld4(q1S + (lx * 17 + (ly + 1)) * TDIM + t0, q1[m]);
            }
            if (aq0) {
                float xpx[4];
                ld4(xbS + ((lx + 2) * R0S + (ly + 1)) * TDIM + t0, xpx);
                #pragma unroll
                for (int j = 0; j < 4; ++j)
                    q0[m][j] = clampl(q0[m][j] + sigma * (xpx[j] - xb[m][j]),
                                      (float)L0r[m][j]);
                st4(q0S + ((lx + 1) * 16 + ly) * TDIM + t0, q0[m]);
            }
            if (aq1) {
                float xpy[4];
                ld4(xbS + ((lx + 1) * R0S + (ly + 2)) * TDIM + t0, xpy);
                #pragma unroll
                for (int j = 0; j < 4; ++j)
                    q1[m][j] = clampl(q1[m][j] + sigma * (xpy[j] - xb[m][j]),
                                      (float)L1r[m][j]);
                st4(q1S + (lx * 17 + (ly + 1)) * TDIM + t0, q1[m]);
            }
            if (ax) {
                float xb_tp = __shfl(xb[m][0], upSrc, 64);
                #pragma unroll
                for (int j = 0; j < 4; ++j) {
                    float gt = ((j < 3) ? xb[m][j + 1] : xb_tp) - xb[m][j];
                    q2[m][j] = clampl(q2[m][j] + sigma * gt, (float)L2r[m][j]);
                    p[m][j]  = (p[m][j] + sigma * (xb[m][j] - (float)XNr[m][j]))
                               * inv1ps;
                }
            }
        }
        __syncthreads();

        #pragma unroll
        for (int m = 0; m < 2; ++m) {
            int line = 128 * m + (tid >> 2);
            int lx = line >> 4, ly = line & 15;
            bool ax = (lx >= lo && lx < hi && ly >= lo && ly < hi);
            if (ax) {
                float q0b[4], q1b[4];
                ld4(q0S + (lx * 16 + ly) * TDIM + t0, q0b);
                ld4(q1S + (lx * 17 + ly) * TDIM + t0, q1b);
                float q2tm = __shfl(q2[m][3], dnSrc, 64);
                #pragma unroll
                for (int j = 0; j < 4; ++j) {
                    float q2p = (j == 0) ? q2tm : q2[m][j - 1];
                    float div = (q0b[j] - q0[m][j]) + (q1b[j] - q1[m][j])
                              + (q2p - q2[m][j]);
                    float xnew = xv[m][j] - tau * (p[m][j] + div);
                    xb[m][j] = xnew + theta * (xnew - xv[m][j]);
                    xv[m][j] = xnew;
                }
                if (k < 4)
                    st4(xbS + ((lx + 1) * R0S + (ly + 1)) * TDIM + t0, xb[m]);
            }
        }
        if (k < 4) __syncthreads();
    }

    #pragma unroll
    for (int m = 0; m < 2; ++m) {
        int line = 128 * m + (tid >> 2);
        int lx = line >> 4, ly = line & 15;
        if (lx >= 3 && lx < 13 && ly >= 3 && ly < 13) {
            int gx = X0 + lx - 3, gy = Y0 + ly - 3;
            int off  = xbase + (gx * YDIM + gy) * TDIM + t0;
            int qoff = qbase + (gx * YDIM + gy) * TDIM + t0;
            st4(pOut + off, p[m]);
            st4(xOut + off, xv[m]);
            half4 h;
            h.x = (hreal)xb[m][0]; h.y = (hreal)xb[m][1];
            h.z = (hreal)xb[m][2]; h.w = (hreal)xb[m][3];
            *(half4*)(xbOut + off) = h;
            h.x = (hreal)q0[m][0]; h.y = (hreal)q0[m][1];
            h.z = (hreal)q0[m][2]; h.w = (hreal)q0[m][3];
            *(half4*)(qOut + qoff) = h;
            h.x = (hreal)q1[m][0]; h.y = (hreal)q1[m][1];
            h.z = (hreal)q1[m][2]; h.w = (hreal)q1[m][3];
            *(half4*)(qOut + qoff + VOL) = h;
            h.x = (hreal)q2[m][0]; h.y = (hreal)q2[m][1];
            h.z = (hreal)q2[m][2]; h.w = (hreal)q2[m][3];
            *(half4*)(qOut + qoff + 2 * VOL) = h;
        }
    }
}

extern "C" void kernel_launch(void* const* d_in, const int* in_sizes, int n_in,
                              void* d_out, int out_size, void* d_ws, size_t ws_size,
                              hipStream_t stream) {
    const float* x   = (const float*)d_in[0];
    const float* lam = (const float*)d_in[1];
    float* out = (float*)d_out;
    float* ws  = (float*)d_ws;

    float* pA  = ws;
    float* pB  = ws + (size_t)NX;
    float* xBb = ws + (size_t)2 * NX;
    float* xAb = out;   // final group (odd parity) writes A family -> d_out
    hreal* hb  = (hreal*)(ws + (size_t)3 * NX);
    hreal* famA = hb;                    // [xb|q0|q1|q2] = 4*NX
    hreal* famB = hb + (size_t)4 * NX;
    hreal* lamh = hb + (size_t)8 * NX;   // 3*NX
    hreal* xnh  = hb + (size_t)11 * NX;  // NX
    unsigned* flags = (unsigned*)(ws + (size_t)9 * NX);

    const size_t ws_need = (size_t)9 * NX * sizeof(float)
                         + (size_t)NBLK * FLAG_STRIDE * sizeof(unsigned);

    const double s10 = 1.0 / (1.0 + exp(-10.0));
    const double L   = sqrt(13.0);
    float sigma  = (float)(s10 / L);
    float tau    = sigma;
    float theta  = (float)s10;
    float inv1ps = (float)(1.0 / (1.0 + s10 / L));

    static int persist_ok = -1;
    if (persist_ok < 0) {
        int nb = 0;
        hipError_t oe = hipOccupancyMaxActiveBlocksPerMultiprocessor(
            &nb, pd_persist, NTHR, 0);
        persist_ok = (oe == hipSuccess && nb >= 2) ? 1 : 0;
        (void)hipGetLastError();
    }
    const bool use_persist = persist_ok == 1 && ws_size >= ws_need;

    init_kernel<<<(3 * NX + 255) / 256, 256, 0, stream>>>(
        x, lam, pA, xAb, famA, lamh, xnh, use_persist ? flags : nullptr);

    if (use_persist) {
        pd_persist<<<NBLK, NTHR, 0, stream>>>(
            xnh, lamh, pA, pB, xAb, xBb, famA, famB, flags,
            sigma, inv1ps, tau, theta);
    } else {
        for (int j = 0; j < NGRP; ++j) {
            const bool e = (j & 1) == 0;
            pd_step4<<<NBLK, NTHR, 0, stream>>>(
                xnh, lamh,
                e ? pA : pB,   e ? pB : pA,
                e ? xAb : xBb, e ? xBb : xAb,
                e ? famA : famB, e ? famB : famA,
                e ? famA + NX : famB + NX, e ? famB + NX : famA + NX,
                sigma, inv1ps, tau, theta);
        }
    }
}

// Round 7
// 252.527 us; speedup vs baseline: 1.0134x; 1.0022x over previous
//
#include <hip/hip_runtime.h>
#include <math.h>

// R14 = R13 skeleton with LDS-LATENCY attack:
//  - All phase-B/C LDS loads hoisted OUT of the aq0/aq1/ax predicates and
//    issued back-to-back at each phase top (addresses are always in-bounds;
//    stores remain predicated; math bit-identical). Collapses 4-6 serial
//    ~120-cycle ds_read exposures per phase into one.
//  - Group-start xb/q0/q1 reloads are unconditional LDS loads (register
//    copy == LDS copy bit-identically; fewer predicates).
//  Everything else (persistent + neighbor flags + XCD-region swizzle +
//  ring-only staging + dead-write trim) identical to R13.
#define XDIM 160
#define YDIM 160
#define TDIM 16
#define NB 2
#define T_ITERS 48
#define TILE 10
#define R1S 16
#define R0S 18
#define TPT (XDIM / TILE)
#define NTHR 512
#define NGRP (T_ITERS / 4)
#define FLAG_STRIDE 16

constexpr int VOL  = XDIM * YDIM * TDIM;  // 409600
constexpr int NX   = NB * VOL;            // 819200
constexpr int NBLK = NB * TPT * TPT;      // 512

// flat LDS arena bases (floats)
constexpr int Q0B = R0S * R0S * TDIM;          // 5184
constexpr int Q1B = Q0B + 17 * 16 * TDIM;      // 9536
constexpr int SLDS = Q1B + 16 * 17 * TDIM;     // 13888 floats = 54.25 KB

typedef _Float16 hreal;
typedef _Float16 half4 __attribute__((ext_vector_type(4)));

__device__ __forceinline__ float clampl(float v, float l) {
    return fminf(fmaxf(v, -l), l);
}
__device__ __forceinline__ int wrap(int v) {
    return v < 0 ? v + XDIM : (v >= XDIM ? v - XDIM : v);
}
__device__ __forceinline__ int wrapT(int v) {
    return v < 0 ? v + TPT : (v >= TPT ? v - TPT : v);
}
__device__ __forceinline__ void ld4(const float* p, float* d) {
    float4 v = *(const float4*)p;
    d[0] = v.x; d[1] = v.y; d[2] = v.z; d[3] = v.w;
}
__device__ __forceinline__ void st4(float* p, const float* s) {
    *(float4*)p = make_float4(s[0], s[1], s[2], s[3]);
}
__device__ __forceinline__ void h2f4(const hreal* p, float* d) {
    half4 v = *(const half4*)p;
    d[0] = (float)v.x; d[1] = (float)v.y; d[2] = (float)v.z; d[3] = (float)v.w;
}
__device__ __forceinline__ float qrot_up(float x) {
    return __int_as_float(__builtin_amdgcn_update_dpp(
        0, __float_as_int(x), 0x39, 0xF, 0xF, true));
}
__device__ __forceinline__ float qrot_dn(float x) {
    return __int_as_float(__builtin_amdgcn_update_dpp(
        0, __float_as_int(x), 0x93, 0xF, 0xF, true));
}

__global__ __launch_bounds__(256) void init_kernel(
    const float* __restrict__ x, const float* __restrict__ lam,
    float* __restrict__ pA, float* __restrict__ xA,
    hreal* __restrict__ famA,          // [xb | q0 | q1 | q2] = 4*NX halves
    hreal* __restrict__ lamh, hreal* __restrict__ xnh,
    unsigned* __restrict__ flags)
{
    int i = blockIdx.x * blockDim.x + threadIdx.x;
    if (i < NX) {
        float v = x[i];
        pA[i] = v; xA[i] = v;
        famA[i] = (hreal)v;            // xb plane
        xnh[i]  = (hreal)v;
    }
    if (i < 3 * NX) {
        famA[NX + i] = (hreal)0.f;     // q planes
        lamh[i] = (hreal)lam[i];
    }
    if (flags && i < NBLK * FLAG_STRIDE) flags[i] = 0u;
}

// ---------------------------------------------------------------------------
// R14 persistent kernel
// ---------------------------------------------------------------------------
__global__
__attribute__((amdgpu_flat_work_group_size(NTHR, NTHR)))
__attribute__((amdgpu_waves_per_eu(4, 4)))
void pd_persist(
    const hreal* __restrict__ xnh, const hreal* __restrict__ lamh,
    float* __restrict__ pA, float* __restrict__ pB,
    float* __restrict__ xA, float* __restrict__ xB,
    hreal* __restrict__ famA, hreal* __restrict__ famB,
    unsigned* __restrict__ flags,
    float sigma, float inv1ps, float tau, float theta)
{
    __shared__ float S[SLDS];

    const int tid = threadIdx.x;
    // XCD-region swizzle: region = bid%8 = {b, tile-quadrant}; 64 tiles each.
    const int region = blockIdx.x & 7;
    const int local  = blockIdx.x >> 3;
    const int b  = region >> 2;
    const int tx = ((region >> 1) & 1) * 8 + (local >> 3);
    const int ty = (region & 1) * 8 + (local & 7);
    const int X0 = tx * TILE, Y0 = ty * TILE;
    const int t0 = (tid & 3) * 4;
    const int QD = NX + 2 * b * VOL;   // xb-plane off -> q0-plane off delta

    const int myFlag = (b * TPT * TPT + tx * TPT + ty) * FLAG_STRIDE;
    const unsigned* nbFlag = nullptr;
    if (tid < 8) {
        const int dxs[8] = {-1,-1,-1, 0, 0, 1, 1, 1};
        const int dys[8] = {-1, 0, 1,-1, 1,-1, 0, 1};
        int nx = wrapT(tx + dxs[tid]);
        int ny = wrapT(ty + dys[tid]);
        nbFlag = flags + (b * TPT * TPT + nx * TPT + ny) * FLAG_STRIDE;
    }

    // loop-carried: p, xv, q2 (+ constants); xb/q0/q1 round-trip through LDS.
    float p[2][4], xv[2][4], q2[2][4];
    float xb[2][4], q0[2][4], q1[2][4];
    half4 XNr[2], L0r[2], L1r[2], L2r[2];
    int lx_[2], ly_[2], ro_[2], so_[2];
    int a_xb[2], a_q0w[2], a_q1w[2];
    bool c_[2], pxs_[2], qs_[2];

    #pragma unroll
    for (int m = 0; m < 2; ++m) {
        int line = 128 * m + (tid >> 2);
        int lx = line >> 4, ly = line & 15;
        lx_[m] = lx; ly_[m] = ly;
        int gx = wrap(X0 - 3 + lx), gy = wrap(Y0 - 3 + ly);
        ro_[m] = b * VOL + (gx * YDIM + gy) * TDIM + t0;
        so_[m] = b * VOL + ((X0 + lx - 3) * YDIM + (Y0 + ly - 3)) * TDIM + t0;
        a_xb[m]  = ((lx + 1) * R0S + (ly + 1)) * TDIM + t0;
        a_q0w[m] = Q0B + ((lx + 1) * 16 + ly) * TDIM + t0;
        a_q1w[m] = Q1B + (lx * 17 + (ly + 1)) * TDIM + t0;
        c_[m]   = lx >= 3 && lx < 13 && ly >= 3 && ly < 13;
        int ox = lx - 3, oy = ly - 3;
        pxs_[m] = (ox >= 3 && ox < 7 && oy >= 3 && oy < 7);
        qs_[m]  = (ox >= 4 && ox < 6 && oy >= 4 && oy < 6);
        int qoff = ro_[m] + 2 * b * VOL;
        XNr[m] = *(const half4*)(xnh + ro_[m]);
        L0r[m] = *(const half4*)(lamh + qoff);
        L1r[m] = *(const half4*)(lamh + qoff + VOL);
        L2r[m] = *(const half4*)(lamh + qoff + 2 * VOL);
    }
    half4 LRr;
    int rQ = 0, rXBC = 0;
    if (tid < 64) {
        int rly = tid >> 2;
        LRr = *(const half4*)(lamh + b * 3 * VOL +
              (wrap(X0 - 4) * YDIM + wrap(Y0 - 3 + rly)) * TDIM + t0);
        rQ   = Q0B + rly * TDIM + t0;
        rXBC = (rly + 1) * TDIM + t0;
    } else if (tid < 128) {
        int rlx = (tid - 64) >> 2;
        LRr = *(const half4*)(lamh + b * 3 * VOL + VOL +
              (wrap(X0 - 3 + rlx) * YDIM + wrap(Y0 - 4)) * TDIM + t0);
        rQ   = Q1B + (rlx * 17) * TDIM + t0;
        rXBC = ((rlx + 1) * R0S) * TDIM + t0;
    }

    #pragma unroll 1
    for (int g = 0; g < NGRP; ++g) {
        const bool e = (g & 1) == 0;
        const bool first = (g == 0);
        const bool fin   = (g == NGRP - 1);
        const float* __restrict__ pIn  = e ? pA : pB;
        float* __restrict__ pOut       = e ? pB : pA;
        const float* __restrict__ xIn  = e ? xA : xB;
        float* __restrict__ xOut       = e ? xB : xA;
        const hreal* __restrict__ famIn = e ? famA : famB;
        hreal* __restrict__ famOut      = e ? famB : famA;

        // ---- neighbor sync: need 8 neighbors' group g-1 epilogues ----
        if (!first) {
            if (tid < 8) {
                const unsigned tgt = (unsigned)g;
                for (unsigned it = 0; it < (1u << 22); ++it) {
                    if (__hip_atomic_load(nbFlag, __ATOMIC_ACQUIRE,
                                          __HIP_MEMORY_SCOPE_AGENT) >= tgt)
                        break;
                    __builtin_amdgcn_s_sleep(1);
                }
            }
            __syncthreads();
            __threadfence();
        }

        // ---- stage halos: full tile on g==0, ring-only afterwards ----
        for (int s = tid; s < R0S * R0S * 4; s += NTHR) {
            int sq = s & 3, ln = s >> 2;
            int rx = ln / R0S, ry = ln % R0S;
            if (!first && rx >= 4 && rx < 14 && ry >= 4 && ry < 14) continue;
            int gx = wrap(X0 - 4 + rx), gy = wrap(Y0 - 4 + ry);
            float v[4];
            h2f4(famIn + b * VOL + (gx * YDIM + gy) * TDIM + sq * 4, v);
            st4(S + ln * TDIM + sq * 4, v);
        }
        for (int s = tid; s < 17 * 16 * 4; s += NTHR) {
            int sq = s & 3, ln = s >> 2;
            int sx = ln / 16, sy = ln % 16;
            if (!first && sx >= 3 && sx < 14 && sy >= 3 && sy < 13) continue;
            int gx = wrap(X0 - 4 + sx), gy = wrap(Y0 - 3 + sy);
            float v[4];
            h2f4(famIn + NX + b * 3 * VOL + (gx * YDIM + gy) * TDIM + sq * 4, v);
            st4(S + Q0B + ln * TDIM + sq * 4, v);
        }
        for (int s = tid; s < 16 * 17 * 4; s += NTHR) {
            int sq = s & 3, ln = s >> 2;
            int sx = ln / 17, sy = ln % 17;
            if (!first && sx >= 3 && sx < 13 && sy >= 3 && sy < 14) continue;
            int gx = wrap(X0 - 3 + sx), gy = wrap(Y0 - 4 + sy);
            float v[4];
            h2f4(famIn + NX + b * 3 * VOL + VOL + (gx * YDIM + gy) * TDIM + sq * 4, v);
            st4(S + Q1B + ln * TDIM + sq * 4, v);
        }

        // ---- per-slot reload of p/xv/q2: ring slots only (center regs are
        //      the ONLY valid copy — global interior is stale by design) ----
        #pragma unroll
        for (int m = 0; m < 2; ++m) {
            if (first || !c_[m]) {
                ld4(pIn + ro_[m], p[m]);
                ld4(xIn + ro_[m], xv[m]);
                h2f4(famIn + ro_[m] + QD + 2 * VOL, q2[m]);
            }
        }
        __syncthreads();

        // xb for ALL slots from LDS (center == last group's fp32 C(k=4) write)
        #pragma unroll
        for (int m = 0; m < 2; ++m)
            ld4(S + a_xb[m], xb[m]);

        // ---- level loop ----
        #pragma unroll
        for (int k = 1; k <= 4; ++k) {
            const int lo = k - 1, hi = 17 - k;

            if (k == 1) {
                // level-1 backward rings (outside R1): q at lx=-1 / ly=-1
                if (tid < 64) {
                    float qr[4], xbc[4], xpx[4];
                    ld4(S + rQ, qr);
                    ld4(S + rXBC, xbc);
                    ld4(S + rXBC + R0S * TDIM, xpx);
                    #pragma unroll
                    for (int j = 0; j < 4; ++j)
                        qr[j] = clampl(qr[j] + sigma * (xpx[j] - xbc[j]), (float)LRr[j]);
                    st4(S + rQ, qr);
                } else if (tid < 128) {
                    float qr[4], xbc[4], xpy[4];
                    ld4(S + rQ, qr);
                    ld4(S + rXBC, xbc);
                    ld4(S + rXBC + TDIM, xpy);
                    #pragma unroll
                    for (int j = 0; j < 4; ++j)
                        qr[j] = clampl(qr[j] + sigma * (xpy[j] - xbc[j]), (float)LRr[j]);
                    st4(S + rQ, qr);
                }
            }

            // ===== phase B: all LDS loads hoisted (unconditional), then
            //       predicated compute + stores =====
            float xpx[2][4], xpy[2][4];
            #pragma unroll
            for (int m = 0; m < 2; ++m) {
                if (k == 1) {                      // unconditional reload
                    ld4(S + a_q0w[m], q0[m]);      // == register value
                    ld4(S + a_q1w[m], q1[m]);
                }
                ld4(S + a_xb[m] + R0S * TDIM, xpx[m]);   // xb(lx+1, ly)
                ld4(S + a_xb[m] + TDIM,       xpy[m]);   // xb(lx, ly+1)
            }
            #pragma unroll
            for (int m = 0; m < 2; ++m) {
                int lx = lx_[m], ly = ly_[m];
                bool inX = (lx >= lo && lx < hi), inY = (ly >= lo && ly < hi);
                bool aq0 = inY && (lx >= lo - 1) && (lx < hi);
                bool aq1 = inX && (ly >= lo - 1) && (ly < hi);

                if (aq0) {
                    #pragma unroll
                    for (int j = 0; j < 4; ++j)
                        q0[m][j] = clampl(q0[m][j] + sigma * (xpx[m][j] - xb[m][j]),
                                          (float)L0r[m][j]);
                    st4(S + a_q0w[m], q0[m]);
                }
                if (aq1) {
                    #pragma unroll
                    for (int j = 0; j < 4; ++j)
                        q1[m][j] = clampl(q1[m][j] + sigma * (xpy[m][j] - xb[m][j]),
                                          (float)L1r[m][j]);
                    st4(S + a_q1w[m], q1[m]);
                }
            }
            __syncthreads();

            // ===== phase C: hoisted backward-q loads, then predicated
            //       q2/p + x/xbar =====
            float q0b[2][4], q1b[2][4];
            #pragma unroll
            for (int m = 0; m < 2; ++m) {
                ld4(S + a_q0w[m] - 16 * TDIM, q0b[m]);   // q0(lx-1, ly)
                ld4(S + a_q1w[m] - TDIM,      q1b[m]);   // q1(lx, ly-1)
            }
            #pragma unroll
            for (int m = 0; m < 2; ++m) {
                int lx = lx_[m], ly = ly_[m];
                bool ax = (lx >= lo && lx < hi && ly >= lo && ly < hi);
                if (ax) {
                    float xb_tp = qrot_up(xb[m][0]);   // xbar at t0+4
                    #pragma unroll
                    for (int j = 0; j < 4; ++j) {
                        float gt = ((j < 3) ? xb[m][j + 1] : xb_tp) - xb[m][j];
                        q2[m][j] = clampl(q2[m][j] + sigma * gt, (float)L2r[m][j]);
                        p[m][j]  = (p[m][j] + sigma * (xb[m][j] - (float)XNr[m][j]))
                                   * inv1ps;
                    }

                    float q2tm = qrot_dn(q2[m][3]);    // new, t0-1
                    #pragma unroll
                    for (int j = 0; j < 4; ++j) {
                        float q2p = (j == 0) ? q2tm : q2[m][j - 1];
                        float div = (q0b[m][j] - q0[m][j]) + (q1b[m][j] - q1[m][j])
                                  + (q2p - q2[m][j]);
                        float xnew = xv[m][j] - tau * (p[m][j] + div);
                        xb[m][j] = xnew + theta * (xnew - xv[m][j]);
                        xv[m][j] = xnew;
                    }
                    // k=4 also stores: keeps LDS center valid across groups
                    st4(S + a_xb[m], xb[m]);
                }
            }
            if (k < 4) __syncthreads();
        }

        // ---- epilogue: only what someone will actually read ----
        #pragma unroll
        for (int m = 0; m < 2; ++m) {
            if (c_[m]) {
                int so = so_[m];
                if (fin) {
                    st4(xOut + so, xv[m]);
                } else {
                    if (!pxs_[m]) {
                        st4(pOut + so, p[m]);
                        st4(xOut + so, xv[m]);
                    }
                    if (!qs_[m]) {
                        half4 h;
                        h.x = (hreal)xb[m][0]; h.y = (hreal)xb[m][1];
                        h.z = (hreal)xb[m][2]; h.w = (hreal)xb[m][3];
                        *(half4*)(famOut + so) = h;
                        h.x = (hreal)q0[m][0]; h.y = (hreal)q0[m][1];
                        h.z = (hreal)q0[m][2]; h.w = (hreal)q0[m][3];
                        *(half4*)(famOut + so + QD) = h;
                        h.x = (hreal)q1[m][0]; h.y = (hreal)q1[m][1];
                        h.z = (hreal)q1[m][2]; h.w = (hreal)q1[m][3];
                        *(half4*)(famOut + so + QD + VOL) = h;
                        h.x = (hreal)q2[m][0]; h.y = (hreal)q2[m][1];
                        h.z = (hreal)q2[m][2]; h.w = (hreal)q2[m][3];
                        *(half4*)(famOut + so + QD + 2 * VOL) = h;
                    }
                }
            }
        }

        if (!fin) {
            __threadfence();
            __syncthreads();
            if (tid == 0)
                __hip_atomic_store(flags + myFlag, (unsigned)(g + 1),
                                   __ATOMIC_RELEASE, __HIP_MEMORY_SCOPE_AGENT);
        }
    }
}

// ---------------------------------------------------------------------------
// Fallback: proven R7 12-launch kernel (family pointers, same semantics)
// ---------------------------------------------------------------------------
__global__ __launch_bounds__(NTHR, 4) void pd_step4(
    const hreal* __restrict__ xnh, const hreal* __restrict__ lamh,
    const float* __restrict__ pIn, float* __restrict__ pOut,
    const float* __restrict__ xIn, float* __restrict__ xOut,
    const hreal* __restrict__ xbIn, hreal* __restrict__ xbOut,
    const hreal* __restrict__ qIn, hreal* __restrict__ qOut,
    float sigma, float inv1ps, float tau, float theta)
{
    __shared__ float xbS[R0S * R0S * TDIM];
    __shared__ float q0S[17 * 16 * TDIM];
    __shared__ float q1S[16 * 17 * TDIM];

    const int tid = threadIdx.x;
    const int b   = blockIdx.x / (TPT * TPT);
    const int rem = blockIdx.x % (TPT * TPT);
    const int X0  = (rem / TPT) * TILE;
    const int Y0  = (rem % TPT) * TILE;
    const int xbase = b * VOL, qbase = b * 3 * VOL;

    const int qd = tid & 3, t0 = qd * 4;
    const int lane  = tid & 63;
    const int upSrc = (lane & 60) | ((lane + 1) & 3);
    const int dnSrc = (lane & 60) | ((lane + 3) & 3);

    for (int s = tid; s < R0S * R0S * 4; s += NTHR) {
        int sq = s & 3, ln = s >> 2;
        int rx = ln / R0S, ry = ln % R0S;
        int gx = wrap(X0 - 4 + rx), gy = wrap(Y0 - 4 + ry);
        float v[4];
        h2f4(xbIn + xbase + (gx * YDIM + gy) * TDIM + sq * 4, v);
        st4(xbS + ln * TDIM + sq * 4, v);
    }
    for (int s = tid; s < 17 * 16 * 4; s += NTHR) {
        int sq = s & 3, ln = s >> 2;
        int sx = ln / 16, sy = ln % 16;
        int gx = wrap(X0 - 4 + sx), gy = wrap(Y0 - 3 + sy);
        float v[4];
        h2f4(qIn + qbase + (gx * YDIM + gy) * TDIM + sq * 4, v);
        st4(q0S + ln * TDIM + sq * 4, v);
    }
    for (int s = tid; s < 16 * 17 * 4; s += NTHR) {
        int sq = s & 3, ln = s >> 2;
        int sx = ln / 17, sy = ln % 17;
        int gx = wrap(X0 - 3 + sx), gy = wrap(Y0 - 4 + sy);
        float v[4];
        h2f4(qIn + qbase + VOL + (gx * YDIM + gy) * TDIM + sq * 4, v);
        st4(q1S + ln * TDIM + sq * 4, v);
    }

    float p[2][4], xv[2][4], xb[2][4], q0[2][4], q1[2][4], q2[2][4];
    half4 XNr[2], L0r[2], L1r[2], L2r[2];
    #pragma unroll
    for (int m = 0; m < 2; ++m) {
        int line = 128 * m + (tid >> 2);
        int lx = line >> 4, ly = line & 15;
        int gx = wrap(X0 - 3 + lx), gy = wrap(Y0 - 3 + ly);
        int off  = xbase + (gx * YDIM + gy) * TDIM + t0;
        int qoff = qbase + (gx * YDIM + gy) * TDIM + t0;
        ld4(pIn + off, p[m]);
        ld4(xIn + off, xv[m]);
        h2f4(qIn + qoff + 2 * VOL, q2[m]);
        XNr[m] = *(const half4*)(xnh + off);
        L0r[m] = *(const half4*)(lamh + qoff);
        L1r[m] = *(const half4*)(lamh + qoff + VOL);
        L2r[m] = *(const half4*)(lamh + qoff + 2 * VOL);
    }

    half4 LRr;
    if (tid < 64) {
        int rly = tid >> 2;
        LRr = *(const half4*)(lamh + qbase +
              (wrap(X0 - 4) * YDIM + wrap(Y0 - 3 + rly)) * TDIM + t0);
    } else if (tid < 128) {
        int rlx = (tid - 64) >> 2;
        LRr = *(const half4*)(lamh + qbase + VOL +
              (wrap(X0 - 3 + rlx) * YDIM + wrap(Y0 - 4)) * TDIM + t0);
    }

    __syncthreads();

    #pragma unroll
    for (int m = 0; m < 2; ++m) {
        int line = 128 * m + (tid >> 2);
        int lx = line >> 4, ly = line & 15;
        ld4(xbS + ((lx + 1) * R0S + (ly + 1)) * TDIM + t0, xb[m]);
    }

    #pragma unroll
    for (int k = 1; k <= 4; ++k) {
        const int lo = k - 1, hi = 17 - k;

        if (k == 1) {
            if (tid < 64) {
                int rly = tid >> 2;
                float qr[4], xbc[4], xpx[4];
                ld4(q0S + rly * TDIM + t0, qr);
                ld4(xbS + (rly + 1) * TDIM + t0, xbc);
                ld4(xbS + (R0S + rly + 1) * TDIM + t0, xpx);
                #pragma unroll
                for (int j = 0; j < 4; ++j)
                    qr[j] = clampl(qr[j] + sigma * (xpx[j] - xbc[j]), (float)LRr[j]);
                st4(q0S + rly * TDIM + t0, qr);
            } else if (tid < 128) {
                int rlx = (tid - 64) >> 2;
                float qr[4], xbc[4], xpy[4];
                ld4(q1S + (rlx * 17) * TDIM + t0, qr);
                ld4(xbS + ((rlx + 1) * R0S) * TDIM + t0, xbc);
                ld4(xbS + ((rlx + 1) * R0S + 1) * TDIM + t0, xpy);
                #pragma unroll
                for (int j = 0; j < 4; ++j)
                    qr[j] = clampl(qr[j] + sigma * (xpy[j] - xbc[j]), (float)LRr[j]);
                st4(q1S + (rlx * 17) * TDIM + t0, qr);
            }
        }

        #pragma unroll
        for (int m = 0; m < 2; ++m) {
            int line = 128 * m + (tid >> 2);
            int lx = line >> 4, ly = line & 15;
            bool inX = (lx >= lo && lx < hi), inY = (ly >= lo && ly < hi);
            bool aq0 = inY && (lx >= lo - 1) && (lx < hi);
            bool aq1 = inX && (ly >= lo - 1) && (ly < hi);
            bool ax  = inX && inY;

            if (k == 1) {
                ld4(q0S + ((lx + 1) * 16 + ly) * TDIM + t0, q0[m]);
                ld4(q1S + (lx * 17 + (ly + 1)) * TDIM + t0, q1[m]);
            }
            if (aq0) {
                float xpx[4];
                ld4(xbS + ((lx + 2) * R0S + (ly + 1)) * TDIM + t0, xpx);
                #pragma unroll
                for (int j = 0; j < 4; ++j)
                    q0[m][j] = clampl(q0[m][j] + sigma * (xpx[j] - xb[m][j]),
                                      (float)L0r[m][j]);
                st4(q0S + ((lx + 1) * 16 + ly) * TDIM + t0, q0[m]);
            }
            if (aq1) {
                float xpy[4];
                ld4(xbS + ((lx + 1) * R0S + (ly + 2)) * TDIM + t0, xpy);
                #pragma unroll
                for (int j = 0; j < 4; ++j)
                    q1[m][j] = clampl(q1[m][j] + sigma * (xpy[j] - xb[m][j]),
                                      (float)L1r[m][j]);
                st4(q1S + (lx * 17 + (ly + 1)) * TDIM + t0, q1[m]);
            }
            if (ax) {
                float xb_tp = __shfl(xb[m][0], upSrc, 64);
                #pragma unroll
                for (int j = 0; j < 4; ++j) {
                    float gt = ((j < 3) ? xb[m][j + 1] : xb_tp) - xb[m][j];
                    q2[m][j] = clampl(q2[m][j] + sigma * gt, (float)L2r[m][j]);
                    p[m][j]  = (p[m][j] + sigma * (xb[m][j] - (float)XNr[m][j]))
                               * inv1ps;
                }
            }
        }
        __syncthreads();

        #pragma unroll
        for (int m = 0; m < 2; ++m) {
            int line = 128 * m + (tid >> 2);
            int lx = line >> 4, ly = line & 15;
            bool ax = (lx >= lo && lx < hi && ly >= lo && ly < hi);
            if (ax) {
                float q0b[4], q1b[4];
                ld4(q0S + (lx * 16 + ly) * TDIM + t0, q0b);
                ld4(q1S + (lx * 17 + ly) * TDIM + t0, q1b);
                float q2tm = __shfl(q2[m][3], dnSrc, 64);
                #pragma unroll
                for (int j = 0; j < 4; ++j) {
                    float q2p = (j == 0) ? q2tm : q2[m][j - 1];
                    float div = (q0b[j] - q0[m][j]) + (q1b[j] - q1[m][j])
                              + (q2p - q2[m][j]);
                    float xnew = xv[m][j] - tau * (p[m][j] + div);
                    xb[m][j] = xnew + theta * (xnew - xv[m][j]);
                    xv[m][j] = xnew;
                }
                if (k < 4)
                    st4(xbS + ((lx + 1) * R0S + (ly + 1)) * TDIM + t0, xb[m]);
            }
        }
        if (k < 4) __syncthreads();
    }

    #pragma unroll
    for (int m = 0; m < 2; ++m) {
        int line = 128 * m + (tid >> 2);
        int lx = line >> 4, ly = line & 15;
        if (lx >= 3 && lx < 13 && ly >= 3 && ly < 13) {
            int gx = X0 + lx - 3, gy = Y0 + ly - 3;
            int off  = xbase + (gx * YDIM + gy) * TDIM + t0;
            int qoff = qbase + (gx * YDIM + gy) * TDIM + t0;
            st4(pOut + off, p[m]);
            st4(xOut + off, xv[m]);
            half4 h;
            h.x = (hreal)xb[m][0]; h.y = (hreal)xb[m][1];
            h.z = (hreal)xb[m][2]; h.w = (hreal)xb[m][3];
            *(half4*)(xbOut + off) = h;
            h.x = (hreal)q0[m][0]; h.y = (hreal)q0[m][1];
            h.z = (hreal)q0[m][2]; h.w = (hreal)q0[m][3];
            *(half4*)(qOut + qoff) = h;
            h.x = (hreal)q1[m][0]; h.y = (hreal)q1[m][1];
            h.z = (hreal)q1[m][2]; h.w = (hreal)q1[m][3];
            *(half4*)(qOut + qoff + VOL) = h;
            h.x = (hreal)q2[m][0]; h.y = (hreal)q2[m][1];
            h.z = (hreal)q2[m][2]; h.w = (hreal)q2[m][3];
            *(half4*)(qOut + qoff + 2 * VOL) = h;
        }
    }
}

extern "C" void kernel_launch(void* const* d_in, const int* in_sizes, int n_in,
                              void* d_out, int out_size, void* d_ws, size_t ws_size,
                              hipStream_t stream) {
    const float* x   = (const float*)d_in[0];
    const float* lam = (const float*)d_in[1];
    float* out = (float*)d_out;
    float* ws  = (float*)d_ws;

    float* pA  = ws;
    float* pB  = ws + (size_t)NX;
    float* xBb = ws + (size_t)2 * NX;
    float* xAb = out;   // final group (odd parity) writes A family -> d_out
    hreal* hb  = (hreal*)(ws + (size_t)3 * NX);
    hreal* famA = hb;                    // [xb|q0|q1|q2] = 4*NX
    hreal* famB = hb + (size_t)4 * NX;
    hreal* lamh = hb + (size_t)8 * NX;   // 3*NX
    hreal* xnh  = hb + (size_t)11 * NX;  // NX
    unsigned* flags = (unsigned*)(ws + (size_t)9 * NX);

    const size_t ws_need = (size_t)9 * NX * sizeof(float)
                         + (size_t)NBLK * FLAG_STRIDE * sizeof(unsigned);

    const double s10 = 1.0 / (1.0 + exp(-10.0));
    const double L   = sqrt(13.0);
    float sigma  = (float)(s10 / L);
    float tau    = sigma;
    float theta  = (float)s10;
    float inv1ps = (float)(1.0 / (1.0 + s10 / L));

    static int persist_ok = -1;
    if (persist_ok < 0) {
        int nb = 0;
        hipError_t oe = hipOccupancyMaxActiveBlocksPerMultiprocessor(
            &nb, pd_persist, NTHR, 0);
        persist_ok = (oe == hipSuccess && nb >= 2) ? 1 : 0;
        (void)hipGetLastError();
    }
    const bool use_persist = persist_ok == 1 && ws_size >= ws_need;

    init_kernel<<<(3 * NX + 255) / 256, 256, 0, stream>>>(
        x, lam, pA, xAb, famA, lamh, xnh, use_persist ? flags : nullptr);

    if (use_persist) {
        pd_persist<<<NBLK, NTHR, 0, stream>>>(
            xnh, lamh, pA, pB, xAb, xBb, famA, famB, flags,
            sigma, inv1ps, tau, theta);
    } else {
        for (int j = 0; j < NGRP; ++j) {
            const bool e = (j & 1) == 0;
            pd_step4<<<NBLK, NTHR, 0, stream>>>(
                xnh, lamh,
                e ? pA : pB,   e ? pB : pA,
                e ? xAb : xBb, e ? xBb : xAb,
                e ? famA : famB, e ? famB : famA,
                e ? famA + NX : famB + NX, e ? famB + NX : famA + NX,
                sigma, inv1ps, tau, theta);
        }
    }
}